// Round 7
// baseline (344.953 us; speedup 1.0000x reference)
//
#include <hip/hip_runtime.h>
#include <hip/hip_bf16.h>
#include <cstdint>
#include <cstddef>

// Problem constants
#define BB   2
#define SS   2048
#define HIDD 2048
#define HH   16
#define KVH  4
#define DD   128
#define NQKV 5120   // H*2*D + KV*D + KV*D = 4096 + 512 + 512
#define MM   4096   // B*S

typedef unsigned short u16t;
typedef __attribute__((ext_vector_type(8))) short s16x8;
typedef __attribute__((ext_vector_type(4))) short s16x4;
typedef __attribute__((ext_vector_type(4))) float f32x4;

__device__ __forceinline__ u16t f2bf(float f) {
  unsigned u = __float_as_uint(f);
  u += 0x7fffu + ((u >> 16) & 1u);
  return (u16t)(u >> 16);
}
__device__ __forceinline__ float bf2f(u16t h) {
  return __uint_as_float(((unsigned)h) << 16);
}
__device__ __forceinline__ void gload_lds16(const void* g, void* l) {
  __builtin_amdgcn_global_load_lds(
      (const __attribute__((address_space(1))) unsigned int*)g,
      (__attribute__((address_space(3))) unsigned int*)l, 16, 0, 0);
}

// ---------------------------------------------------------------- cast f32->bf16
__global__ __launch_bounds__(256) void cast_x(const float* __restrict__ in,
                                              u16t* __restrict__ out) {
  size_t i = ((size_t)blockIdx.x * 256 + threadIdx.x) * 4;
  f32x4 v = *(const f32x4*)(in + i);
  s16x4 o;
  o[0] = (short)f2bf(v[0]); o[1] = (short)f2bf(v[1]);
  o[2] = (short)f2bf(v[2]); o[3] = (short)f2bf(v[3]);
  *(s16x4*)(out + i) = o;
}

// -------------------------------------------- transpose-cast W (K=2048,N) -> Wt (N,2048) bf16
__global__ __launch_bounds__(256) void transpose_cast(const float* __restrict__ src,
                                                      u16t* __restrict__ dst, int N) {
  __shared__ float lds[64 * 65];
  int t = threadIdx.x;
  const int ktiles = HIDD / 64; // 32
  int n0 = (blockIdx.x / ktiles) << 6;
  int k0 = (blockIdx.x % ktiles) << 6;
#pragma unroll
  for (int i = 0; i < 16; i++) {
    int idx = i * 256 + t;
    int r = idx >> 6, c = idx & 63;
    lds[c * 65 + r] = src[(size_t)(k0 + r) * N + n0 + c];
  }
  __syncthreads();
#pragma unroll
  for (int i = 0; i < 16; i++) {
    int idx = i * 256 + t;
    int rr = idx >> 6, kk = idx & 63;
    dst[(size_t)(n0 + rr) * HIDD + k0 + kk] = f2bf(lds[rr * 65 + kk]);
  }
}

// ---------------------------------------------------------------- 128x128 bf16 GEMM (m97 structure)
// C(MxN, CT) = A(MxK,bf16 rm) @ Bt(NxK,bf16 rm)^T.  BK=32.
template <typename CT>
__global__ __launch_bounds__(256) void gemm_bt(const u16t* __restrict__ A,
                                               const u16t* __restrict__ Bt,
                                               CT* __restrict__ C,
                                               int M, int N, int K) {
  __shared__ __align__(16) char As[128 * 64];
  __shared__ __align__(16) char Bs[128 * 64];
  int tid = threadIdx.x;
  int lane = tid & 63;
  int w = tid >> 6;
  // XCD-chunked bijective swizzle (grid % 8 == 0)
  int cpx = gridDim.x >> 3;
  int wgid = ((int)blockIdx.x & 7) * cpx + ((int)blockIdx.x >> 3);
  int mtiles = M >> 7;
  int bm = wgid % mtiles;
  int bn = wgid / mtiles;
  int m0 = bm << 7, n0 = bn << 7;
  int wr = (w >> 1) * 64, wc = (w & 1) * 64;

  const f32x4 fz = {0.f, 0.f, 0.f, 0.f};
  f32x4 acc[4][4];
#pragma unroll
  for (int i = 0; i < 4; i++)
#pragma unroll
    for (int j = 0; j < 4; j++) acc[i][j] = fz;

  for (int k0 = 0; k0 < K; k0 += 32) {
    __syncthreads();
#pragma unroll
    for (int i = 0; i < 2; i++) {
      int idx = i * 256 + tid;
      int r = idx >> 2, c = idx & 3;
      int csrc = c ^ ((r >> 1) & 3);          // 2-way swizzle (bank-free)
      gload_lds16(A + (size_t)(m0 + r) * K + k0 + csrc * 8, As + idx * 16);
      gload_lds16(Bt + (size_t)(n0 + r) * K + k0 + csrc * 8, Bs + idx * 16);
    }
    __syncthreads();
    s16x8 af[4], bf[4];
    int g = lane >> 4;
#pragma unroll
    for (int mi = 0; mi < 4; mi++) {
      int r = wr + mi * 16 + (lane & 15);
      af[mi] = *(const s16x8*)(As + r * 64 + ((g ^ ((r >> 1) & 3)) << 4));
    }
#pragma unroll
    for (int ni = 0; ni < 4; ni++) {
      int r = wc + ni * 16 + (lane & 15);
      bf[ni] = *(const s16x8*)(Bs + r * 64 + ((g ^ ((r >> 1) & 3)) << 4));
    }
#pragma unroll
    for (int mi = 0; mi < 4; mi++)
#pragma unroll
      for (int ni = 0; ni < 4; ni++)
        acc[mi][ni] = __builtin_amdgcn_mfma_f32_16x16x32_bf16(af[mi], bf[ni], acc[mi][ni], 0, 0, 0);
  }
#pragma unroll
  for (int mi = 0; mi < 4; mi++)
#pragma unroll
    for (int ni = 0; ni < 4; ni++) {
      int row0 = m0 + wr + mi * 16 + ((lane >> 4) << 2);
      int col = n0 + wc + ni * 16 + (lane & 15);
#pragma unroll
      for (int j = 0; j < 4; j++) {
        if constexpr (sizeof(CT) == 2)
          C[(size_t)(row0 + j) * N + col] = f2bf(acc[mi][ni][j]);
        else
          C[(size_t)(row0 + j) * N + col] = acc[mi][ni][j];
      }
    }
}

// ------------------------------------------------- fused RMSNorm + RoPE for Q and K
__global__ __launch_bounds__(256) void qk_norm_rope(const u16t* __restrict__ Cqkv,
                                                    const float* __restrict__ rope,
                                                    const float* __restrict__ qw,
                                                    const float* __restrict__ kw,
                                                    u16t* __restrict__ Qb,   // (B,H,S,D)
                                                    u16t* __restrict__ Kb,   // (B,KV,S,D)
                                                    u16t* __restrict__ Gs,   // (B,S,H*D)
                                                    float* __restrict__ present) {
  int wid = blockIdx.x * 4 + (threadIdx.x >> 6);
  int lane = threadIdx.x & 63;
  const int NQ = BB * SS * HH; // 65536
  if (wid < NQ) {
    int b = wid >> 15;          // S*H = 32768
    int rem = wid & 32767;
    int s = rem >> 4, h = rem & 15;
    const u16t* base = Cqkv + (size_t)(b * SS + s) * NQKV + h * 256;
    float xlo = bf2f(base[lane]), xhi = bf2f(base[64 + lane]);
    float ss = xlo * xlo + xhi * xhi;
    ss += __shfl_xor(ss, 1);  ss += __shfl_xor(ss, 2);  ss += __shfl_xor(ss, 4);
    ss += __shfl_xor(ss, 8);  ss += __shfl_xor(ss, 16); ss += __shfl_xor(ss, 32);
    float r = rsqrtf(ss * (1.f / 128.f) + 1e-6f);
    float qlo = xlo * r * (1.f + qw[lane]);
    float qhi = xhi * r * (1.f + qw[64 + lane]);
    const float* cs = rope + (size_t)s * 256;
    float clo = cs[lane], chi = cs[64 + lane];
    float slo = cs[128 + lane], shi = cs[192 + lane];
    const float SC = 0.08838834764831845f; // 1/sqrt(128), folded into Q
    float olo = (qlo * clo - qhi * slo) * SC;
    float ohi = (qhi * chi + qlo * shi) * SC;
    size_t qoff = (((size_t)b * HH + h) * SS + s) * DD;
    Qb[qoff + lane] = f2bf(olo);
    Qb[qoff + 64 + lane] = f2bf(ohi);
    float glo = bf2f(base[128 + lane]), ghi = bf2f(base[192 + lane]);
    size_t goff = ((size_t)(b * SS + s)) * (HH * DD) + h * DD;
    Gs[goff + lane] = f2bf(1.f / (1.f + __expf(-glo)));
    Gs[goff + 64 + lane] = f2bf(1.f / (1.f + __expf(-ghi)));
  } else {
    int wid2 = wid - NQ;        // (b, s, kv): per b = S*KV = 8192
    int b = wid2 >> 13;
    int rem = wid2 & 8191;
    int s = rem >> 2, kv = rem & 3;
    const u16t* base = Cqkv + (size_t)(b * SS + s) * NQKV + 4096 + kv * 128;
    float xlo = bf2f(base[lane]), xhi = bf2f(base[64 + lane]);
    float ss = xlo * xlo + xhi * xhi;
    ss += __shfl_xor(ss, 1);  ss += __shfl_xor(ss, 2);  ss += __shfl_xor(ss, 4);
    ss += __shfl_xor(ss, 8);  ss += __shfl_xor(ss, 16); ss += __shfl_xor(ss, 32);
    float r = rsqrtf(ss * (1.f / 128.f) + 1e-6f);
    float klo = xlo * r * (1.f + kw[lane]);
    float khi = xhi * r * (1.f + kw[64 + lane]);
    const float* cs = rope + (size_t)s * 256;
    float clo = cs[lane], chi = cs[64 + lane];
    float slo = cs[128 + lane], shi = cs[192 + lane];
    float olo = klo * clo - khi * slo;
    float ohi = khi * chi + klo * shi;
    size_t koff = (((size_t)b * KVH + kv) * SS + s) * DD;
    Kb[koff + lane] = f2bf(olo);
    Kb[koff + 64 + lane] = f2bf(ohi);
    // present[b][0][kv][s][d]
    size_t poff = (((size_t)(b * 2 * KVH + kv)) * SS + s) * DD;
    present[poff + lane] = olo;
    present[poff + 64 + lane] = ohi;
  }
}

// ------------------------------------------------- V: present write + V^T bf16 (B,KV,D,S)
__global__ __launch_bounds__(256) void v_write(const u16t* __restrict__ Cqkv,
                                               float* __restrict__ present,
                                               u16t* __restrict__ Vtb) {
  __shared__ float lds[128 * 65];
  int t = threadIdx.x;
  int b = blockIdx.x >> 7;
  int kv = (blockIdx.x >> 5) & 3;
  int s0 = (blockIdx.x & 31) << 6;
#pragma unroll
  for (int i = 0; i < 32; i++) {
    int idx = i * 256 + t;
    int sp = idx >> 7, d = idx & 127;
    float v = bf2f(Cqkv[(size_t)(b * SS + s0 + sp) * NQKV + 4608 + kv * 128 + d]);
    // present[b][1][kv][s][d]
    present[(((size_t)(b * 2 * KVH + KVH + kv)) * SS + s0 + sp) * DD + d] = v;
    lds[d * 65 + sp] = v;
  }
  __syncthreads();
#pragma unroll
  for (int i = 0; i < 8; i++) {
    int d = i * 16 + (t >> 4);
    int sp = (t & 15) * 4;
    s16x4 pk;
    pk[0] = (short)f2bf(lds[d * 65 + sp + 0]);
    pk[1] = (short)f2bf(lds[d * 65 + sp + 1]);
    pk[2] = (short)f2bf(lds[d * 65 + sp + 2]);
    pk[3] = (short)f2bf(lds[d * 65 + sp + 3]);
    *(s16x4*)(Vtb + ((size_t)(b * KVH + kv) * DD + d) * SS + s0 + sp) = pk;
  }
}

// ---------------------------------------------------------------- flash attention v3
// block = 4 waves (wave = 16 q-rows); QBLK=64; KVBLK=32; causal.
// LDS = Ks dbuf 16K + Vs dbuf 16K + Ps 4K = 36 KB; __launch_bounds__(256,3)
// -> ~3 waves/SIMD (12 waves/CU): 1.5x chain overlap vs round-5 structure.
// Grid 1024 (b2 x h16 x qt32): capacity ~768 resident + 256 queued -> real
// backfill; LPT order (qt descending within each XCD chunk) so stragglers start
// first. XCD x = bid&7 owns (b,kv): KV stays L2-resident per XCD.
// K/V double-buffered: stage kt+1 at top, one vmcnt(0)+barrier per tile.
__global__ __launch_bounds__(256, 3) void attn_kernel(const u16t* __restrict__ Qb,   // (B,H,S,D) pre-scaled
                                                      const u16t* __restrict__ Kb,   // (B,KV,S,D)
                                                      const u16t* __restrict__ Vtb,  // (B,KV,D,S)
                                                      const u16t* __restrict__ Gs,   // (B,S,H*D)
                                                      u16t* __restrict__ AttG) {     // (B,S,H*D)
  __shared__ __align__(16) char Ks[2][8192];   // 32 k-rows x 256B, chunk xor (r&7)
  __shared__ __align__(16) char Vs[2][8192];   // V^T: 128 d-rows x 64B, chunk xor ((r>>1)&3)
  __shared__ __align__(16) char Ps[4][1024];   // per-wave P: 16 q-rows x 64B, chunk xor ((r>>1)&3)

  int tid = threadIdx.x, lane = tid & 63, w = tid >> 6;
  int x = blockIdx.x & 7;          // XCD grouping: each XCD owns one (b,kv)
  int b = x >> 2, kv = x & 3;
  int k = blockIdx.x >> 3;         // 0..127 within XCD, dispatched in order
  int h = kv * 4 + (k & 3);
  int qt = 31 - (k >> 2);          // LPT: largest q-tiles dispatched first

  const u16t* Kbase = Kb + (((size_t)(b * KVH + kv)) * SS) * DD;
  const u16t* Vbase = Vtb + (((size_t)(b * KVH + kv)) * DD) * SS;

  auto stageK = [&](int kt, int buf) {   // 8KB: 32 rows x 128 bf16
#pragma unroll
    for (int i = 0; i < 2; i++) {
      int idx = i * 256 + tid;
      int r_ = idx >> 4, c_ = idx & 15;
      gload_lds16(Kbase + (size_t)(kt * 32 + r_) * DD + (c_ ^ (r_ & 7)) * 8, Ks[buf] + idx * 16);
    }
  };
  auto stageV = [&](int kt, int buf) {   // 8KB: 128 d-rows x 32 bf16
#pragma unroll
    for (int i = 0; i < 2; i++) {
      int idx = i * 256 + tid;
      int r_ = idx >> 2, c_ = idx & 3;
      int cs = c_ ^ ((r_ >> 1) & 3);
      gload_lds16(Vbase + (size_t)r_ * SS + kt * 32 + cs * 8, Vs[buf] + idx * 16);
    }
  };

  const f32x4 fz = {0.f, 0.f, 0.f, 0.f};
  char* pbase = Ps[w];
  int cur = 0;
  const int nkt = 2 * qt + 2;      // 32-wide k-tiles

  // prologue: stage tile 0
  stageK(0, 0);
  stageV(0, 0);

  // Q fragments straight from global (pre-scaled by 1/sqrt(D))
  s16x8 qf[4];
  {
    const u16t* qrow = Qb + (((size_t)(b * HH + h)) * SS + qt * 64 + w * 16 + (lane & 15)) * DD
                       + (lane >> 4) * 8;
#pragma unroll
    for (int ks = 0; ks < 4; ks++) qf[ks] = *(const s16x8*)(qrow + ks * 32);
  }
  f32x4 acco[8];
#pragma unroll
  for (int f = 0; f < 8; f++) acco[f] = fz;
  float mrun[4], lrun[4];
#pragma unroll
  for (int j = 0; j < 4; j++) { mrun[j] = -INFINITY; lrun[j] = 0.f; }

  asm volatile("s_waitcnt vmcnt(0)" ::: "memory");
  __builtin_amdgcn_s_barrier();

  for (int kt = 0; kt < nkt; kt++) {
    if (kt + 1 < nkt) {              // stage next tile into other buffer
      stageK(kt + 1, cur ^ 1);
      stageV(kt + 1, cur ^ 1);
    }
    // ---- QK^T from Ks[cur]: accs[2] (32 k-cols)
    f32x4 accs[2];
#pragma unroll
    for (int ni = 0; ni < 2; ni++) accs[ni] = fz;
#pragma unroll
    for (int ni = 0; ni < 2; ni++) {
      int r = ni * 16 + (lane & 15);
#pragma unroll
      for (int ks = 0; ks < 4; ks++) {
        int g = ks * 4 + (lane >> 4);
        s16x8 bfk = *(const s16x8*)(Ks[cur] + r * 256 + ((g ^ (r & 7)) << 4));
        accs[ni] = __builtin_amdgcn_mfma_f32_16x16x32_bf16(qf[ks], bfk, accs[ni], 0, 0, 0);
      }
    }
    if (kt >= 2 * qt) {              // diagonal k-tiles
#pragma unroll
      for (int ni = 0; ni < 2; ni++) {
        int kglob = kt * 32 + ni * 16 + (lane & 15);
#pragma unroll
        for (int j = 0; j < 4; j++) {
          int qglob = qt * 64 + w * 16 + ((lane >> 4) << 2) + j;
          if (kglob > qglob) accs[ni][j] = -1e30f;
        }
      }
    }
    // ---- online softmax (16-lane row groups)
    float mt[4];
#pragma unroll
    for (int j = 0; j < 4; j++) {
      float v = fmaxf(accs[0][j], accs[1][j]);
      v = fmaxf(v, __shfl_xor(v, 1));
      v = fmaxf(v, __shfl_xor(v, 2));
      v = fmaxf(v, __shfl_xor(v, 4));
      v = fmaxf(v, __shfl_xor(v, 8));
      mt[j] = v;
    }
    float alpha[4];
#pragma unroll
    for (int j = 0; j < 4; j++) {
      float mnew = fmaxf(mrun[j], mt[j]);
      alpha[j] = __expf(mrun[j] - mnew);
      mrun[j] = mnew;
    }
    float rs[4] = {0.f, 0.f, 0.f, 0.f};
#pragma unroll
    for (int ni = 0; ni < 2; ni++)
#pragma unroll
      for (int j = 0; j < 4; j++) {
        float pv = __expf(accs[ni][j] - mrun[j]);
        accs[ni][j] = pv;
        rs[j] += pv;
      }
#pragma unroll
    for (int j = 0; j < 4; j++) {
      float v = rs[j];
      v += __shfl_xor(v, 1); v += __shfl_xor(v, 2);
      v += __shfl_xor(v, 4); v += __shfl_xor(v, 8);
      lrun[j] = lrun[j] * alpha[j] + v;
    }
#pragma unroll
    for (int f = 0; f < 8; f++)
#pragma unroll
      for (int j = 0; j < 4; j++) acco[f][j] *= alpha[j];

    // ---- P -> per-wave LDS: row=q (16), col=k (32), 64B rows, chunk xor ((row>>1)&3)
#pragma unroll
    for (int ni = 0; ni < 2; ni++)
#pragma unroll
      for (int j = 0; j < 4; j++) {
        int row = ((lane >> 4) << 2) + j, col = ni * 16 + (lane & 15);
        int ch = (col >> 3) ^ ((row >> 1) & 3);
        *(u16t*)(pbase + row * 64 + ch * 16 + (col & 7) * 2) = f2bf(accs[ni][j]);
      }
    // ---- PV from Vs[cur]: single K=32 step
    {
      int pr = lane & 15;
      int pch = (lane >> 4) ^ ((pr >> 1) & 3);
      s16x8 pa = *(const s16x8*)(pbase + pr * 64 + (pch << 4));
#pragma unroll
      for (int f = 0; f < 8; f++) {
        int d = f * 16 + (lane & 15);
        int vch = (lane >> 4) ^ ((d >> 1) & 3);
        s16x8 vf = *(const s16x8*)(Vs[cur] + d * 64 + (vch << 4));
        acco[f] = __builtin_amdgcn_mfma_f32_16x16x32_bf16(pa, vf, acco[f], 0, 0, 0);
      }
    }
    // ---- tile boundary
    if (kt + 1 < nkt) {
      asm volatile("s_waitcnt vmcnt(0)" ::: "memory");
      __builtin_amdgcn_s_barrier();
      cur ^= 1;
    }
  }
  // ---- epilogue: gate + store
#pragma unroll
  for (int f = 0; f < 8; f++) {
    int d = f * 16 + (lane & 15);
#pragma unroll
    for (int j = 0; j < 4; j++) {
      int srow = qt * 64 + w * 16 + ((lane >> 4) << 2) + j;
      float o = acco[f][j] / lrun[j];
      size_t off = ((size_t)b * SS + srow) * (HH * DD) + h * DD + d;
      float g = bf2f(Gs[off]);
      AttG[off] = f2bf(o * g);
    }
  }
}

// ---------------------------------------------------------------- launcher
extern "C" void kernel_launch(void* const* d_in, const int* in_sizes, int n_in,
                              void* d_out, int out_size, void* d_ws, size_t ws_size,
                              hipStream_t stream) {
  const float* hidden = (const float*)d_in[0];
  const float* rope   = (const float*)d_in[2];
  const float* Wq     = (const float*)d_in[5];
  const float* Wk     = (const float*)d_in[6];
  const float* Wv     = (const float*)d_in[7];
  const float* Wo     = (const float*)d_in[8];
  const float* qw     = (const float*)d_in[9];
  const float* kw     = (const float*)d_in[10];
  float* out = (float*)d_out;
  float* present = out + (size_t)BB * SS * HIDD; // 8,388,608

  char* ws = (char*)d_ws;
  u16t* Xb    = (u16t*)(ws);                              // 4096x2048 bf16   16.78MB
  u16t* Wt    = (u16t*)(ws + 16777216);                   // 5120x2048 bf16   20.97MB
  u16t* Wot   = (u16t*)(ws + 37748736);                   // 2048x2048 bf16    8.39MB
  u16t* Cqkv  = (u16t*)(ws + 46137344);                   // 4096x5120 bf16   41.94MB
  u16t* Qb    = (u16t*)(ws + 88080384);                   // (B,H,S,D) bf16   16.78MB
  u16t* Kb    = (u16t*)(ws + 104857600);                  // (B,KV,S,D) bf16   4.19MB
  u16t* Vtb   = (u16t*)(ws + 109051904);                  // (B,KV,D,S) bf16   4.19MB
  u16t* Gs    = (u16t*)(ws + 113246208);                  // (B,S,H*D) bf16   16.78MB
  u16t* AttG  = Xb;  // alias: Xb dead after QKV GEMM; AttG written by attention

  // 1. cast hidden -> bf16
  cast_x<<<8192, 256, 0, stream>>>(hidden, Xb);
  // 2. transpose-cast weights into B^T layout
  transpose_cast<<<(4096 / 64) * 32, 256, 0, stream>>>(Wq, Wt, 4096);
  transpose_cast<<<(512 / 64) * 32, 256, 0, stream>>>(Wk, Wt + (size_t)4096 * HIDD, 512);
  transpose_cast<<<(512 / 64) * 32, 256, 0, stream>>>(Wv, Wt + (size_t)4608 * HIDD, 512);
  transpose_cast<<<(2048 / 64) * 32, 256, 0, stream>>>(Wo, Wot, 2048);
  // 3. QKV projection: 128^2 m97-structure GEMM, grid 32x40 = 1280
  gemm_bt<u16t><<<(MM / 128) * (NQKV / 128), 256, 0, stream>>>(Xb, Wt, Cqkv, MM, NQKV, HIDD);
  // 4. Q/K norm+rope (+present K, +sigmoid gate); V writer (+present V, +V^T)
  qk_norm_rope<<<(BB * SS * (HH + KVH)) / 4, 256, 0, stream>>>(Cqkv, rope, qw, kw, Qb, Kb, Gs, present);
  v_write<<<BB * KVH * (SS / 64), 256, 0, stream>>>(Cqkv, present, Vtb);
  // 5. flash attention v3: KVBLK=32, grid 1024, LPT + backfill
  attn_kernel<<<BB * HH * (SS / 64), 256, 0, stream>>>(Qb, Kb, Vtb, Gs, AttG);
  // 6. output projection -> d_out: grid 32x16 = 512
  gemm_bt<float><<<(MM / 128) * (HIDD / 128), 256, 0, stream>>>(AttG, Wot, out, MM, HIDD, HIDD);
}

// Round 8
// 309.873 us; speedup vs baseline: 1.1132x; 1.1132x over previous
//
#include <hip/hip_runtime.h>
#include <hip/hip_bf16.h>
#include <cstdint>
#include <cstddef>

// Problem constants
#define BB   2
#define SS   2048
#define HIDD 2048
#define HH   16
#define KVH  4
#define DD   128
#define NQKV 5120   // H*2*D + KV*D + KV*D = 4096 + 512 + 512
#define MM   4096   // B*S

typedef unsigned short u16t;
typedef __attribute__((ext_vector_type(8))) short s16x8;
typedef __attribute__((ext_vector_type(4))) short s16x4;
typedef __attribute__((ext_vector_type(4))) float f32x4;

__device__ __forceinline__ u16t f2bf(float f) {
  unsigned u = __float_as_uint(f);
  u += 0x7fffu + ((u >> 16) & 1u);
  return (u16t)(u >> 16);
}
__device__ __forceinline__ float bf2f(u16t h) {
  return __uint_as_float(((unsigned)h) << 16);
}
__device__ __forceinline__ void gload_lds16(const void* g, void* l) {
  __builtin_amdgcn_global_load_lds(
      (const __attribute__((address_space(1))) unsigned int*)g,
      (__attribute__((address_space(3))) unsigned int*)l, 16, 0, 0);
}

// ---------------------------------------------------------------- cast f32->bf16
__global__ __launch_bounds__(256) void cast_x(const float* __restrict__ in,
                                              u16t* __restrict__ out) {
  size_t i = ((size_t)blockIdx.x * 256 + threadIdx.x) * 4;
  f32x4 v = *(const f32x4*)(in + i);
  s16x4 o;
  o[0] = (short)f2bf(v[0]); o[1] = (short)f2bf(v[1]);
  o[2] = (short)f2bf(v[2]); o[3] = (short)f2bf(v[3]);
  *(s16x4*)(out + i) = o;
}

// -------------------------------------------- transpose-cast W (K=2048,N) -> Wt (N,2048) bf16
__global__ __launch_bounds__(256) void transpose_cast(const float* __restrict__ src,
                                                      u16t* __restrict__ dst, int N) {
  __shared__ float lds[64 * 65];
  int t = threadIdx.x;
  const int ktiles = HIDD / 64; // 32
  int n0 = (blockIdx.x / ktiles) << 6;
  int k0 = (blockIdx.x % ktiles) << 6;
#pragma unroll
  for (int i = 0; i < 16; i++) {
    int idx = i * 256 + t;
    int r = idx >> 6, c = idx & 63;
    lds[c * 65 + r] = src[(size_t)(k0 + r) * N + n0 + c];
  }
  __syncthreads();
#pragma unroll
  for (int i = 0; i < 16; i++) {
    int idx = i * 256 + t;
    int rr = idx >> 6, kk = idx & 63;
    dst[(size_t)(n0 + rr) * HIDD + k0 + kk] = f2bf(lds[rr * 65 + kk]);
  }
}

// ---------------------------------------------------------------- 256x256 8-phase bf16 GEMM
// C(M x n, CT; row-stride N) = A(MxK) @ Bt(nxK)^T.  BK=64 (2 K-halves of 32).
// grid = (M/256) * (n/256); M/256 must be 16. Use with grid % 256 == 0 for balance.
__device__ __forceinline__ s16x8 ldsfrag(const char* half, int r, int g) {
  return *(const s16x8*)(half + r * 64 + ((g ^ ((r >> 1) & 3)) << 4));
}
__device__ __forceinline__ void stage_half(char* ldsbase, const u16t* gbase,
                                           int K, int kcol, int tid) {
#pragma unroll
  for (int i = 0; i < 2; i++) {
    int o16 = i * 512 + tid;
    int r = o16 >> 2;
    int cs = (o16 & 3) ^ ((r >> 1) & 3);
    gload_lds16(gbase + (size_t)r * K + kcol + cs * 8, ldsbase + o16 * 16);
  }
}

template <typename CT>
__global__ __launch_bounds__(512, 2) void gemm8(const u16t* __restrict__ A,
                                                const u16t* __restrict__ Bt,
                                                CT* __restrict__ C,
                                                int M, int N, int K) {
  extern __shared__ __align__(16) char lds[];
  char* As = lds;           // [slot:32768][kk:16384]
  char* Bs = lds + 65536;
  int tid = threadIdx.x, lane = tid & 63, w = tid >> 6;
  int wm = w >> 2, wn = w & 3;
  int cpx = gridDim.x >> 3;                       // grid % 8 == 0
  int wgid = (blockIdx.x & 7) * cpx + (blockIdx.x >> 3);
  int bm = wgid & 15, bn = wgid >> 4;             // M/256 == 16
  int m0 = bm << 8, n0 = bn << 8;
  const u16t* Ag = A + (size_t)m0 * K;
  const u16t* Bg = Bt + (size_t)n0 * K;
  const int NT = K >> 6;

  // prologue: Ah0(0) Bh0(0) Ah1(0) Bh1(0) Ah0(1) Bh0(1)  (12 loads)
  stage_half(As, Ag, K, 0, tid);
  stage_half(Bs, Bg, K, 0, tid);
  stage_half(As + 16384, Ag, K, 32, tid);
  stage_half(Bs + 16384, Bg, K, 32, tid);
  stage_half(As + 32768, Ag, K, 64, tid);
  stage_half(Bs + 32768, Bg, K, 64, tid);
  asm volatile("s_waitcnt vmcnt(8)" ::: "memory");
  __builtin_amdgcn_s_barrier();

  const f32x4 fz = {0.f, 0.f, 0.f, 0.f};
  f32x4 acc[8][4];
#pragma unroll
  for (int i = 0; i < 8; i++)
#pragma unroll
    for (int j = 0; j < 4; j++) acc[i][j] = fz;
  s16x8 afr[4], bfr[4];
  int g = lane >> 4;
  int rA = (lane & 15) + wm * 128;
  int rB = (lane & 15) + wn * 64;

  for (int kt = 0; kt < NT; kt++) {
    int cur = kt & 1;
    char* Acur = As + cur * 32768;
    char* Bcur = Bs + cur * 32768;
    char* Anxt = As + (cur ^ 1) * 32768;
    char* Bnxt = Bs + (cur ^ 1) * 32768;
    // ---- phase 0: (kk0, mh0); stage Ah1(kt+1)
#pragma unroll
    for (int ni = 0; ni < 4; ni++) bfr[ni] = ldsfrag(Bcur, rB + ni * 16, g);
#pragma unroll
    for (int mi = 0; mi < 4; mi++) afr[mi] = ldsfrag(Acur, rA + mi * 16, g);
    if (kt + 1 < NT) stage_half(Anxt + 16384, Ag, K, (kt + 1) * 64 + 32, tid);
    __builtin_amdgcn_s_barrier();
    asm volatile("s_waitcnt lgkmcnt(0)" ::: "memory");
    __builtin_amdgcn_s_setprio(1);
#pragma unroll
    for (int mi = 0; mi < 4; mi++)
#pragma unroll
      for (int ni = 0; ni < 4; ni++)
        acc[mi][ni] = __builtin_amdgcn_mfma_f32_16x16x32_bf16(afr[mi], bfr[ni], acc[mi][ni], 0, 0, 0);
    __builtin_amdgcn_s_setprio(0);
    __builtin_amdgcn_s_barrier();
    // ---- phase 1: (kk0, mh1); stage Bh1(kt+1); counted wait
#pragma unroll
    for (int mi = 0; mi < 4; mi++) afr[mi] = ldsfrag(Acur, rA + 64 + mi * 16, g);
    if (kt + 1 < NT) stage_half(Bnxt + 16384, Bg, K, (kt + 1) * 64 + 32, tid);
    __builtin_amdgcn_s_barrier();
    asm volatile("s_waitcnt lgkmcnt(0)" ::: "memory");
    __builtin_amdgcn_s_setprio(1);
#pragma unroll
    for (int mi = 0; mi < 4; mi++)
#pragma unroll
      for (int ni = 0; ni < 4; ni++)
        acc[4 + mi][ni] = __builtin_amdgcn_mfma_f32_16x16x32_bf16(afr[mi], bfr[ni], acc[4 + mi][ni], 0, 0, 0);
    __builtin_amdgcn_s_setprio(0);
    if (kt + 1 < NT) asm volatile("s_waitcnt vmcnt(8)" ::: "memory");
    else             asm volatile("s_waitcnt vmcnt(0)" ::: "memory");
    __builtin_amdgcn_s_barrier();
    // ---- phase 2: (kk1, mh0); stage Ah0(kt+2)
#pragma unroll
    for (int ni = 0; ni < 4; ni++) bfr[ni] = ldsfrag(Bcur + 16384, rB + ni * 16, g);
#pragma unroll
    for (int mi = 0; mi < 4; mi++) afr[mi] = ldsfrag(Acur + 16384, rA + mi * 16, g);
    if (kt + 2 < NT) stage_half(Acur, Ag, K, (kt + 2) * 64, tid);
    __builtin_amdgcn_s_barrier();
    asm volatile("s_waitcnt lgkmcnt(0)" ::: "memory");
    __builtin_amdgcn_s_setprio(1);
#pragma unroll
    for (int mi = 0; mi < 4; mi++)
#pragma unroll
      for (int ni = 0; ni < 4; ni++)
        acc[mi][ni] = __builtin_amdgcn_mfma_f32_16x16x32_bf16(afr[mi], bfr[ni], acc[mi][ni], 0, 0, 0);
    __builtin_amdgcn_s_setprio(0);
    __builtin_amdgcn_s_barrier();
    // ---- phase 3: (kk1, mh1); stage Bh0(kt+2); counted wait
#pragma unroll
    for (int mi = 0; mi < 4; mi++) afr[mi] = ldsfrag(Acur + 16384, rA + 64 + mi * 16, g);
    if (kt + 2 < NT) stage_half(Bcur, Bg, K, (kt + 2) * 64, tid);
    __builtin_amdgcn_s_barrier();
    asm volatile("s_waitcnt lgkmcnt(0)" ::: "memory");
    __builtin_amdgcn_s_setprio(1);
#pragma unroll
    for (int mi = 0; mi < 4; mi++)
#pragma unroll
      for (int ni = 0; ni < 4; ni++)
        acc[4 + mi][ni] = __builtin_amdgcn_mfma_f32_16x16x32_bf16(afr[mi], bfr[ni], acc[4 + mi][ni], 0, 0, 0);
    __builtin_amdgcn_s_setprio(0);
    if (kt < NT - 1) {
      if (kt + 2 < NT) asm volatile("s_waitcnt vmcnt(8)" ::: "memory");
      else             asm volatile("s_waitcnt vmcnt(4)" ::: "memory");
    }
    __builtin_amdgcn_s_barrier();
  }
  // epilogue: C write
#pragma unroll
  for (int mi = 0; mi < 8; mi++)
#pragma unroll
    for (int ni = 0; ni < 4; ni++) {
      int row0 = m0 + wm * 128 + mi * 16 + ((lane >> 4) << 2);
      int col = n0 + wn * 64 + ni * 16 + (lane & 15);
#pragma unroll
      for (int j = 0; j < 4; j++) {
        if constexpr (sizeof(CT) == 2)
          C[(size_t)(row0 + j) * N + col] = f2bf(acc[mi][ni][j]);
        else
          C[(size_t)(row0 + j) * N + col] = acc[mi][ni][j];
      }
    }
}

// ---------------------------------------------------------------- 128x128 bf16 GEMM (m97 structure)
// C(M x n, CT; row-stride N) = A(MxK) @ Bt(nxK)^T.  BK=32. grid=(M/128)*(n/128).
template <typename CT>
__global__ __launch_bounds__(256) void gemm_bt(const u16t* __restrict__ A,
                                               const u16t* __restrict__ Bt,
                                               CT* __restrict__ C,
                                               int M, int N, int K) {
  __shared__ __align__(16) char As[128 * 64];
  __shared__ __align__(16) char Bs[128 * 64];
  int tid = threadIdx.x;
  int lane = tid & 63;
  int w = tid >> 6;
  // XCD-chunked bijective swizzle (grid % 8 == 0)
  int cpx = gridDim.x >> 3;
  int wgid = ((int)blockIdx.x & 7) * cpx + ((int)blockIdx.x >> 3);
  int mtiles = M >> 7;
  int bm = wgid % mtiles;
  int bn = wgid / mtiles;
  int m0 = bm << 7, n0 = bn << 7;
  int wr = (w >> 1) * 64, wc = (w & 1) * 64;

  const f32x4 fz = {0.f, 0.f, 0.f, 0.f};
  f32x4 acc[4][4];
#pragma unroll
  for (int i = 0; i < 4; i++)
#pragma unroll
    for (int j = 0; j < 4; j++) acc[i][j] = fz;

  for (int k0 = 0; k0 < K; k0 += 32) {
    __syncthreads();
#pragma unroll
    for (int i = 0; i < 2; i++) {
      int idx = i * 256 + tid;
      int r = idx >> 2, c = idx & 3;
      int csrc = c ^ ((r >> 1) & 3);          // 2-way swizzle (bank-free)
      gload_lds16(A + (size_t)(m0 + r) * K + k0 + csrc * 8, As + idx * 16);
      gload_lds16(Bt + (size_t)(n0 + r) * K + k0 + csrc * 8, Bs + idx * 16);
    }
    __syncthreads();
    s16x8 af[4], bf[4];
    int g = lane >> 4;
#pragma unroll
    for (int mi = 0; mi < 4; mi++) {
      int r = wr + mi * 16 + (lane & 15);
      af[mi] = *(const s16x8*)(As + r * 64 + ((g ^ ((r >> 1) & 3)) << 4));
    }
#pragma unroll
    for (int ni = 0; ni < 4; ni++) {
      int r = wc + ni * 16 + (lane & 15);
      bf[ni] = *(const s16x8*)(Bs + r * 64 + ((g ^ ((r >> 1) & 3)) << 4));
    }
#pragma unroll
    for (int mi = 0; mi < 4; mi++)
#pragma unroll
      for (int ni = 0; ni < 4; ni++)
        acc[mi][ni] = __builtin_amdgcn_mfma_f32_16x16x32_bf16(af[mi], bf[ni], acc[mi][ni], 0, 0, 0);
  }
#pragma unroll
  for (int mi = 0; mi < 4; mi++)
#pragma unroll
    for (int ni = 0; ni < 4; ni++) {
      int row0 = m0 + wr + mi * 16 + ((lane >> 4) << 2);
      int col = n0 + wc + ni * 16 + (lane & 15);
#pragma unroll
      for (int j = 0; j < 4; j++) {
        if constexpr (sizeof(CT) == 2)
          C[(size_t)(row0 + j) * N + col] = f2bf(acc[mi][ni][j]);
        else
          C[(size_t)(row0 + j) * N + col] = acc[mi][ni][j];
      }
    }
}

// ------------------------------------------------- fused RMSNorm + RoPE for Q and K
__global__ __launch_bounds__(256) void qk_norm_rope(const u16t* __restrict__ Cqkv,
                                                    const float* __restrict__ rope,
                                                    const float* __restrict__ qw,
                                                    const float* __restrict__ kw,
                                                    u16t* __restrict__ Qb,   // (B,H,S,D)
                                                    u16t* __restrict__ Kb,   // (B,KV,S,D)
                                                    u16t* __restrict__ Gs,   // (B,S,H*D)
                                                    float* __restrict__ present) {
  int wid = blockIdx.x * 4 + (threadIdx.x >> 6);
  int lane = threadIdx.x & 63;
  const int NQ = BB * SS * HH; // 65536
  if (wid < NQ) {
    int b = wid >> 15;          // S*H = 32768
    int rem = wid & 32767;
    int s = rem >> 4, h = rem & 15;
    const u16t* base = Cqkv + (size_t)(b * SS + s) * NQKV + h * 256;
    float xlo = bf2f(base[lane]), xhi = bf2f(base[64 + lane]);
    float ss = xlo * xlo + xhi * xhi;
    ss += __shfl_xor(ss, 1);  ss += __shfl_xor(ss, 2);  ss += __shfl_xor(ss, 4);
    ss += __shfl_xor(ss, 8);  ss += __shfl_xor(ss, 16); ss += __shfl_xor(ss, 32);
    float r = rsqrtf(ss * (1.f / 128.f) + 1e-6f);
    float qlo = xlo * r * (1.f + qw[lane]);
    float qhi = xhi * r * (1.f + qw[64 + lane]);
    const float* cs = rope + (size_t)s * 256;
    float clo = cs[lane], chi = cs[64 + lane];
    float slo = cs[128 + lane], shi = cs[192 + lane];
    const float SC = 0.08838834764831845f; // 1/sqrt(128), folded into Q
    float olo = (qlo * clo - qhi * slo) * SC;
    float ohi = (qhi * chi + qlo * shi) * SC;
    size_t qoff = (((size_t)b * HH + h) * SS + s) * DD;
    Qb[qoff + lane] = f2bf(olo);
    Qb[qoff + 64 + lane] = f2bf(ohi);
    float glo = bf2f(base[128 + lane]), ghi = bf2f(base[192 + lane]);
    size_t goff = ((size_t)(b * SS + s)) * (HH * DD) + h * DD;
    Gs[goff + lane] = f2bf(1.f / (1.f + __expf(-glo)));
    Gs[goff + 64 + lane] = f2bf(1.f / (1.f + __expf(-ghi)));
  } else {
    int wid2 = wid - NQ;        // (b, s, kv): per b = S*KV = 8192
    int b = wid2 >> 13;
    int rem = wid2 & 8191;
    int s = rem >> 2, kv = rem & 3;
    const u16t* base = Cqkv + (size_t)(b * SS + s) * NQKV + 4096 + kv * 128;
    float xlo = bf2f(base[lane]), xhi = bf2f(base[64 + lane]);
    float ss = xlo * xlo + xhi * xhi;
    ss += __shfl_xor(ss, 1);  ss += __shfl_xor(ss, 2);  ss += __shfl_xor(ss, 4);
    ss += __shfl_xor(ss, 8);  ss += __shfl_xor(ss, 16); ss += __shfl_xor(ss, 32);
    float r = rsqrtf(ss * (1.f / 128.f) + 1e-6f);
    float klo = xlo * r * (1.f + kw[lane]);
    float khi = xhi * r * (1.f + kw[64 + lane]);
    const float* cs = rope + (size_t)s * 256;
    float clo = cs[lane], chi = cs[64 + lane];
    float slo = cs[128 + lane], shi = cs[192 + lane];
    float olo = klo * clo - khi * slo;
    float ohi = khi * chi + klo * shi;
    size_t koff = (((size_t)b * KVH + kv) * SS + s) * DD;
    Kb[koff + lane] = f2bf(olo);
    Kb[koff + 64 + lane] = f2bf(ohi);
    // present[b][0][kv][s][d]
    size_t poff = (((size_t)(b * 2 * KVH + kv)) * SS + s) * DD;
    present[poff + lane] = olo;
    present[poff + 64 + lane] = ohi;
  }
}

// ------------------------------------------------- V: present write + V^T bf16 (B,KV,D,S)
__global__ __launch_bounds__(256) void v_write(const u16t* __restrict__ Cqkv,
                                               float* __restrict__ present,
                                               u16t* __restrict__ Vtb) {
  __shared__ float lds[128 * 65];
  int t = threadIdx.x;
  int b = blockIdx.x >> 7;
  int kv = (blockIdx.x >> 5) & 3;
  int s0 = (blockIdx.x & 31) << 6;
#pragma unroll
  for (int i = 0; i < 32; i++) {
    int idx = i * 256 + t;
    int sp = idx >> 7, d = idx & 127;
    float v = bf2f(Cqkv[(size_t)(b * SS + s0 + sp) * NQKV + 4608 + kv * 128 + d]);
    // present[b][1][kv][s][d]
    present[(((size_t)(b * 2 * KVH + KVH + kv)) * SS + s0 + sp) * DD + d] = v;
    lds[d * 65 + sp] = v;
  }
  __syncthreads();
#pragma unroll
  for (int i = 0; i < 8; i++) {
    int d = i * 16 + (t >> 4);
    int sp = (t & 15) * 4;
    s16x4 pk;
    pk[0] = (short)f2bf(lds[d * 65 + sp + 0]);
    pk[1] = (short)f2bf(lds[d * 65 + sp + 1]);
    pk[2] = (short)f2bf(lds[d * 65 + sp + 2]);
    pk[3] = (short)f2bf(lds[d * 65 + sp + 3]);
    *(s16x4*)(Vtb + ((size_t)(b * KVH + kv) * DD + d) * SS + s0 + sp) = pk;
  }
}

// ---------------------------------------------------------------- flash attention (round-6 proven)
// block = 4 waves; KVBLK=64; causal. PAIRED q-tiles: qt = 31-p then p -> 33
// KV-tile-units per block, every block equal. Grid 512 = 2 blocks/CU.
// K/V double-buffered (LDS 72KB): stage next tile at top, one vmcnt(0)+barrier/tile.
__global__ __launch_bounds__(256) void attn_kernel(const u16t* __restrict__ Qb,   // (B,H,S,D) pre-scaled
                                                   const u16t* __restrict__ Kb,   // (B,KV,S,D)
                                                   const u16t* __restrict__ Vtb,  // (B,KV,D,S)
                                                   const u16t* __restrict__ Gs,   // (B,S,H*D)
                                                   u16t* __restrict__ AttG) {     // (B,S,H*D)
  __shared__ __align__(16) char Ks[2][16384];   // 64 rows x 256B, chunk xor (r&7)
  __shared__ __align__(16) char Vs[2][16384];   // V^T: 128 rows x 128B, chunk xor (d&7)
  __shared__ __align__(16) char Ps[4 * 2048];   // per-wave P: 16 rows x 128B, chunk xor

  int tid = threadIdx.x, lane = tid & 63, w = tid >> 6;
  int x = blockIdx.x & 7;          // XCD grouping: each XCD owns one (b,kv)
  int b = x >> 2, kv = x & 3;
  int rr = blockIdx.x >> 3;        // 0..63
  int h = kv * 4 + (rr & 3);
  int p = rr >> 2;                 // 0..15: pair {31-p, p}

  const u16t* Kbase = Kb + (((size_t)(b * KVH + kv)) * SS) * DD;
  const u16t* Vbase = Vtb + (((size_t)(b * KVH + kv)) * DD) * SS;

  auto stageK = [&](int kt, int buf) {
#pragma unroll
    for (int i = 0; i < 4; i++) {
      int idx = i * 256 + tid;
      int r_ = idx >> 4, c_ = idx & 15;
      gload_lds16(Kbase + (size_t)(kt * 64 + r_) * DD + (c_ ^ (r_ & 7)) * 8, Ks[buf] + idx * 16);
    }
  };
  auto stageV = [&](int kt, int buf) {
#pragma unroll
    for (int i = 0; i < 4; i++) {
      int idx = i * 256 + tid;
      int r_ = idx >> 3, c_ = idx & 7;
      gload_lds16(Vbase + (size_t)r_ * SS + kt * 64 + (c_ ^ (r_ & 7)) * 8, Vs[buf] + idx * 16);
    }
  };

  const f32x4 fz = {0.f, 0.f, 0.f, 0.f};
  char* pbase = Ps + w * 2048;
  int cur = 0;

  // prologue: stage tile 0 of segment 0 into buffer 0
  stageK(0, 0);
  stageV(0, 0);

  for (int seg = 0; seg < 2; seg++) {
    int qt = (seg == 0) ? (31 - p) : p;
    const u16t* Qbase = Qb + (((size_t)(b * HH + h)) * SS + qt * 64) * DD;
    s16x8 qf[4];
    {
      const u16t* qrow = Qbase + (size_t)(w * 16 + (lane & 15)) * DD + (lane >> 4) * 8;
#pragma unroll
      for (int ks = 0; ks < 4; ks++) qf[ks] = *(const s16x8*)(qrow + ks * 32);
    }
    f32x4 acco[8];
#pragma unroll
    for (int f = 0; f < 8; f++) acco[f] = fz;
    float mrun[4], lrun[4];
#pragma unroll
    for (int j = 0; j < 4; j++) { mrun[j] = -INFINITY; lrun[j] = 0.f; }

    if (seg == 0) {
      asm volatile("s_waitcnt vmcnt(0)" ::: "memory");
      __builtin_amdgcn_s_barrier();
    }

    for (int kt = 0; kt <= qt; kt++) {
      bool havenext = (kt < qt) || (seg == 0);
      if (havenext) {
        int nk = (kt < qt) ? (kt + 1) : 0;   // next tile, or seg1's tile 0
        stageK(nk, cur ^ 1);
        stageV(nk, cur ^ 1);
      }
      // ---- QK^T from Ks[cur]
      f32x4 accs[4];
#pragma unroll
      for (int ni = 0; ni < 4; ni++) accs[ni] = fz;
#pragma unroll
      for (int ni = 0; ni < 4; ni++) {
        int r = ni * 16 + (lane & 15);
#pragma unroll
        for (int ks = 0; ks < 4; ks++) {
          int g = ks * 4 + (lane >> 4);
          s16x8 bfk = *(const s16x8*)(Ks[cur] + r * 256 + ((g ^ (r & 7)) << 4));
          accs[ni] = __builtin_amdgcn_mfma_f32_16x16x32_bf16(qf[ks], bfk, accs[ni], 0, 0, 0);
        }
      }
      if (kt == qt) {
#pragma unroll
        for (int ni = 0; ni < 4; ni++) {
          int col = ni * 16 + (lane & 15);
#pragma unroll
          for (int j = 0; j < 4; j++) {
            int row = w * 16 + ((lane >> 4) << 2) + j;
            if (col > row) accs[ni][j] = -1e30f;
          }
        }
      }
      // ---- online softmax
      float mt[4];
#pragma unroll
      for (int j = 0; j < 4; j++) {
        float v = fmaxf(fmaxf(accs[0][j], accs[1][j]), fmaxf(accs[2][j], accs[3][j]));
        v = fmaxf(v, __shfl_xor(v, 1));
        v = fmaxf(v, __shfl_xor(v, 2));
        v = fmaxf(v, __shfl_xor(v, 4));
        v = fmaxf(v, __shfl_xor(v, 8));
        mt[j] = v;
      }
      float alpha[4];
#pragma unroll
      for (int j = 0; j < 4; j++) {
        float mnew = fmaxf(mrun[j], mt[j]);
        alpha[j] = __expf(mrun[j] - mnew);
        mrun[j] = mnew;
      }
      float rs[4] = {0.f, 0.f, 0.f, 0.f};
#pragma unroll
      for (int ni = 0; ni < 4; ni++)
#pragma unroll
        for (int j = 0; j < 4; j++) {
          float pv = __expf(accs[ni][j] - mrun[j]);
          accs[ni][j] = pv;
          rs[j] += pv;
        }
#pragma unroll
      for (int j = 0; j < 4; j++) {
        float v = rs[j];
        v += __shfl_xor(v, 1); v += __shfl_xor(v, 2);
        v += __shfl_xor(v, 4); v += __shfl_xor(v, 8);
        lrun[j] = lrun[j] * alpha[j] + v;
      }
#pragma unroll
      for (int f = 0; f < 8; f++)
#pragma unroll
        for (int j = 0; j < 4; j++) acco[f][j] *= alpha[j];

      // ---- P -> LDS (per-wave region)
#pragma unroll
      for (int ni = 0; ni < 4; ni++)
#pragma unroll
        for (int j = 0; j < 4; j++) {
          int row = ((lane >> 4) << 2) + j, col = ni * 16 + (lane & 15);
          int ch = (col >> 3) ^ (row & 7);
          *(u16t*)(pbase + row * 128 + ch * 16 + (col & 7) * 2) = f2bf(accs[ni][j]);
        }
      // ---- PV from Vs[cur]
#pragma unroll
      for (int ks = 0; ks < 2; ks++) {
        int pr = lane & 15;
        int pch = (ks * 4 + (lane >> 4)) ^ (pr & 7);
        s16x8 pa = *(const s16x8*)(pbase + pr * 128 + (pch << 4));
#pragma unroll
        for (int f = 0; f < 8; f++) {
          int d = f * 16 + (lane & 15);
          int g = ks * 4 + (lane >> 4);
          s16x8 vf = *(const s16x8*)(Vs[cur] + d * 128 + ((g ^ (d & 7)) << 4));
          acco[f] = __builtin_amdgcn_mfma_f32_16x16x32_bf16(pa, vf, acco[f], 0, 0, 0);
        }
      }
      // ---- tile boundary: next tile staged, current reads done
      if (havenext) {
        asm volatile("s_waitcnt vmcnt(0)" ::: "memory");
        __builtin_amdgcn_s_barrier();
        cur ^= 1;
      }
    }
    // ---- segment epilogue
#pragma unroll
    for (int f = 0; f < 8; f++) {
      int d = f * 16 + (lane & 15);
#pragma unroll
      for (int j = 0; j < 4; j++) {
        int srow = qt * 64 + w * 16 + ((lane >> 4) << 2) + j;
        float o = acco[f][j] / lrun[j];
        size_t off = ((size_t)b * SS + srow) * (HH * DD) + h * DD + d;
        float g = bf2f(Gs[off]);
        AttG[off] = f2bf(o * g);
      }
    }
  }
}

// ---------------------------------------------------------------- launcher
extern "C" void kernel_launch(void* const* d_in, const int* in_sizes, int n_in,
                              void* d_out, int out_size, void* d_ws, size_t ws_size,
                              hipStream_t stream) {
  const float* hidden = (const float*)d_in[0];
  const float* rope   = (const float*)d_in[2];
  const float* Wq     = (const float*)d_in[5];
  const float* Wk     = (const float*)d_in[6];
  const float* Wv     = (const float*)d_in[7];
  const float* Wo     = (const float*)d_in[8];
  const float* qw     = (const float*)d_in[9];
  const float* kw     = (const float*)d_in[10];
  float* out = (float*)d_out;
  float* present = out + (size_t)BB * SS * HIDD; // 8,388,608

  char* ws = (char*)d_ws;
  u16t* Xb    = (u16t*)(ws);                              // 4096x2048 bf16   16.78MB
  u16t* Wt    = (u16t*)(ws + 16777216);                   // 5120x2048 bf16   20.97MB
  u16t* Wot   = (u16t*)(ws + 37748736);                   // 2048x2048 bf16    8.39MB
  u16t* Cqkv  = (u16t*)(ws + 46137344);                   // 4096x5120 bf16   41.94MB
  u16t* Qb    = (u16t*)(ws + 88080384);                   // (B,H,S,D) bf16   16.78MB
  u16t* Kb    = (u16t*)(ws + 104857600);                  // (B,KV,S,D) bf16   4.19MB
  u16t* Vtb   = (u16t*)(ws + 109051904);                  // (B,KV,D,S) bf16   4.19MB
  u16t* Gs    = (u16t*)(ws + 113246208);                  // (B,S,H*D) bf16   16.78MB
  u16t* AttG  = Xb;  // alias: Xb dead after QKV GEMM; AttG written by attention

  // allow 128KiB dynamic LDS for gemm8
  (void)hipFuncSetAttribute(reinterpret_cast<const void*>(gemm8<u16t>),
                            hipFuncAttributeMaxDynamicSharedMemorySize, 131072);

  // 1. cast hidden -> bf16
  cast_x<<<8192, 256, 0, stream>>>(hidden, Xb);
  // 2. transpose-cast weights into B^T layout
  transpose_cast<<<(4096 / 64) * 32, 256, 0, stream>>>(Wq, Wt, 4096);
  transpose_cast<<<(512 / 64) * 32, 256, 0, stream>>>(Wk, Wt + (size_t)4096 * HIDD, 512);
  transpose_cast<<<(512 / 64) * 32, 256, 0, stream>>>(Wv, Wt + (size_t)4608 * HIDD, 512);
  transpose_cast<<<(2048 / 64) * 32, 256, 0, stream>>>(Wo, Wot, 2048);
  // 3a. Q projection (N=4096): 256^2 8-phase, grid 16x16 = 256 = exactly 1 block/CU
  gemm8<u16t><<<(MM / 256) * (4096 / 256), 512, 131072, stream>>>(Xb, Wt, Cqkv, MM, NQKV, HIDD);
  // 3b. K+V projection (N=1024): 128^2 m97, grid 32x8 = 256 = exactly 1 block/CU
  gemm_bt<u16t><<<(MM / 128) * (1024 / 128), 256, 0, stream>>>(
      Xb, Wt + (size_t)4096 * HIDD, Cqkv + 4096, MM, NQKV, HIDD);
  // 4. Q/K norm+rope (+present K, +sigmoid gate); V writer (+present V, +V^T)
  qk_norm_rope<<<(BB * SS * (HH + KVH)) / 4, 256, 0, stream>>>(Cqkv, rope, qw, kw, Qb, Kb, Gs, present);
  v_write<<<BB * KVH * (SS / 64), 256, 0, stream>>>(Cqkv, present, Vtb);
  // 5. flash attention: paired q-tiles, 512 uniform blocks (round-6 proven)
  attn_kernel<<<BB * HH * (SS / 128), 256, 0, stream>>>(Qb, Kb, Vtb, Gs, AttG);
  // 6. output projection -> d_out: 128^2 m97, grid 32x16 = 512 = 2 blocks/CU
  gemm_bt<float><<<(MM / 128) * (HIDD / 128), 256, 0, stream>>>(AttG, Wot, out, MM, HIDD, HIDD);
}

// Round 9
// 291.917 us; speedup vs baseline: 1.1817x; 1.0615x over previous
//
#include <hip/hip_runtime.h>
#include <hip/hip_bf16.h>
#include <cstdint>
#include <cstddef>

// Problem constants
#define BB   2
#define SS   2048
#define HIDD 2048
#define HH   16
#define KVH  4
#define DD   128
#define NQKV 5120   // H*2*D + KV*D + KV*D = 4096 + 512 + 512
#define MM   4096   // B*S

typedef unsigned short u16t;
typedef __attribute__((ext_vector_type(8))) short s16x8;
typedef __attribute__((ext_vector_type(4))) short s16x4;
typedef __attribute__((ext_vector_type(4))) float f32x4;

__device__ __forceinline__ u16t f2bf(float f) {
  unsigned u = __float_as_uint(f);
  u += 0x7fffu + ((u >> 16) & 1u);
  return (u16t)(u >> 16);
}
__device__ __forceinline__ float bf2f(u16t h) {
  return __uint_as_float(((unsigned)h) << 16);
}
__device__ __forceinline__ void gload_lds16(const void* g, void* l) {
  __builtin_amdgcn_global_load_lds(
      (const __attribute__((address_space(1))) unsigned int*)g,
      (__attribute__((address_space(3))) unsigned int*)l, 16, 0, 0);
}
__device__ __forceinline__ unsigned cvtpk_bf16(float lo, float hi) {
  unsigned r;
  asm("v_cvt_pk_bf16_f32 %0, %1, %2" : "=v"(r) : "v"(lo), "v"(hi));
  return r;
}
__device__ __forceinline__ f32x4 fmax4(f32x4 a, f32x4 b) {
  f32x4 r;
  r[0] = fmaxf(a[0], b[0]); r[1] = fmaxf(a[1], b[1]);
  r[2] = fmaxf(a[2], b[2]); r[3] = fmaxf(a[3], b[3]);
  return r;
}

// ---------------------------------------------------------------- cast f32->bf16
__global__ __launch_bounds__(256) void cast_x(const float* __restrict__ in,
                                              u16t* __restrict__ out) {
  size_t i = ((size_t)blockIdx.x * 256 + threadIdx.x) * 4;
  f32x4 v = *(const f32x4*)(in + i);
  s16x4 o;
  o[0] = (short)f2bf(v[0]); o[1] = (short)f2bf(v[1]);
  o[2] = (short)f2bf(v[2]); o[3] = (short)f2bf(v[3]);
  *(s16x4*)(out + i) = o;
}

// -------------------------------------------- transpose-cast W (K=2048,N) -> Wt (N,2048) bf16
__global__ __launch_bounds__(256) void transpose_cast(const float* __restrict__ src,
                                                      u16t* __restrict__ dst, int N) {
  __shared__ float lds[64 * 65];
  int t = threadIdx.x;
  const int ktiles = HIDD / 64; // 32
  int n0 = (blockIdx.x / ktiles) << 6;
  int k0 = (blockIdx.x % ktiles) << 6;
#pragma unroll
  for (int i = 0; i < 16; i++) {
    int idx = i * 256 + t;
    int r = idx >> 6, c = idx & 63;
    lds[c * 65 + r] = src[(size_t)(k0 + r) * N + n0 + c];
  }
  __syncthreads();
#pragma unroll
  for (int i = 0; i < 16; i++) {
    int idx = i * 256 + t;
    int rr = idx >> 6, kk = idx & 63;
    dst[(size_t)(n0 + rr) * HIDD + k0 + kk] = f2bf(lds[rr * 65 + kk]);
  }
}

// ---------------------------------------------------------------- 256x256 8-phase bf16 GEMM
__device__ __forceinline__ s16x8 ldsfrag(const char* half, int r, int g) {
  return *(const s16x8*)(half + r * 64 + ((g ^ ((r >> 1) & 3)) << 4));
}
__device__ __forceinline__ void stage_half(char* ldsbase, const u16t* gbase,
                                           int K, int kcol, int tid) {
#pragma unroll
  for (int i = 0; i < 2; i++) {
    int o16 = i * 512 + tid;
    int r = o16 >> 2;
    int cs = (o16 & 3) ^ ((r >> 1) & 3);
    gload_lds16(gbase + (size_t)r * K + kcol + cs * 8, ldsbase + o16 * 16);
  }
}

template <typename CT>
__global__ __launch_bounds__(512, 2) void gemm8(const u16t* __restrict__ A,
                                                const u16t* __restrict__ Bt,
                                                CT* __restrict__ C,
                                                int M, int N, int K) {
  extern __shared__ __align__(16) char lds[];
  char* As = lds;           // [slot:32768][kk:16384]
  char* Bs = lds + 65536;
  int tid = threadIdx.x, lane = tid & 63, w = tid >> 6;
  int wm = w >> 2, wn = w & 3;
  int cpx = gridDim.x >> 3;                       // grid % 8 == 0
  int wgid = (blockIdx.x & 7) * cpx + (blockIdx.x >> 3);
  int bm = wgid & 15, bn = wgid >> 4;             // M/256 == 16
  int m0 = bm << 8, n0 = bn << 8;
  const u16t* Ag = A + (size_t)m0 * K;
  const u16t* Bg = Bt + (size_t)n0 * K;
  const int NT = K >> 6;

  stage_half(As, Ag, K, 0, tid);
  stage_half(Bs, Bg, K, 0, tid);
  stage_half(As + 16384, Ag, K, 32, tid);
  stage_half(Bs + 16384, Bg, K, 32, tid);
  stage_half(As + 32768, Ag, K, 64, tid);
  stage_half(Bs + 32768, Bg, K, 64, tid);
  asm volatile("s_waitcnt vmcnt(8)" ::: "memory");
  __builtin_amdgcn_s_barrier();

  const f32x4 fz = {0.f, 0.f, 0.f, 0.f};
  f32x4 acc[8][4];
#pragma unroll
  for (int i = 0; i < 8; i++)
#pragma unroll
    for (int j = 0; j < 4; j++) acc[i][j] = fz;
  s16x8 afr[4], bfr[4];
  int g = lane >> 4;
  int rA = (lane & 15) + wm * 128;
  int rB = (lane & 15) + wn * 64;

  for (int kt = 0; kt < NT; kt++) {
    int cur = kt & 1;
    char* Acur = As + cur * 32768;
    char* Bcur = Bs + cur * 32768;
    char* Anxt = As + (cur ^ 1) * 32768;
    char* Bnxt = Bs + (cur ^ 1) * 32768;
    // ---- phase 0
#pragma unroll
    for (int ni = 0; ni < 4; ni++) bfr[ni] = ldsfrag(Bcur, rB + ni * 16, g);
#pragma unroll
    for (int mi = 0; mi < 4; mi++) afr[mi] = ldsfrag(Acur, rA + mi * 16, g);
    if (kt + 1 < NT) stage_half(Anxt + 16384, Ag, K, (kt + 1) * 64 + 32, tid);
    __builtin_amdgcn_s_barrier();
    asm volatile("s_waitcnt lgkmcnt(0)" ::: "memory");
    __builtin_amdgcn_s_setprio(1);
#pragma unroll
    for (int mi = 0; mi < 4; mi++)
#pragma unroll
      for (int ni = 0; ni < 4; ni++)
        acc[mi][ni] = __builtin_amdgcn_mfma_f32_16x16x32_bf16(afr[mi], bfr[ni], acc[mi][ni], 0, 0, 0);
    __builtin_amdgcn_s_setprio(0);
    __builtin_amdgcn_s_barrier();
    // ---- phase 1
#pragma unroll
    for (int mi = 0; mi < 4; mi++) afr[mi] = ldsfrag(Acur, rA + 64 + mi * 16, g);
    if (kt + 1 < NT) stage_half(Bnxt + 16384, Bg, K, (kt + 1) * 64 + 32, tid);
    __builtin_amdgcn_s_barrier();
    asm volatile("s_waitcnt lgkmcnt(0)" ::: "memory");
    __builtin_amdgcn_s_setprio(1);
#pragma unroll
    for (int mi = 0; mi < 4; mi++)
#pragma unroll
      for (int ni = 0; ni < 4; ni++)
        acc[4 + mi][ni] = __builtin_amdgcn_mfma_f32_16x16x32_bf16(afr[mi], bfr[ni], acc[4 + mi][ni], 0, 0, 0);
    __builtin_amdgcn_s_setprio(0);
    if (kt + 1 < NT) asm volatile("s_waitcnt vmcnt(8)" ::: "memory");
    else             asm volatile("s_waitcnt vmcnt(0)" ::: "memory");
    __builtin_amdgcn_s_barrier();
    // ---- phase 2
#pragma unroll
    for (int ni = 0; ni < 4; ni++) bfr[ni] = ldsfrag(Bcur + 16384, rB + ni * 16, g);
#pragma unroll
    for (int mi = 0; mi < 4; mi++) afr[mi] = ldsfrag(Acur + 16384, rA + mi * 16, g);
    if (kt + 2 < NT) stage_half(Acur, Ag, K, (kt + 2) * 64, tid);
    __builtin_amdgcn_s_barrier();
    asm volatile("s_waitcnt lgkmcnt(0)" ::: "memory");
    __builtin_amdgcn_s_setprio(1);
#pragma unroll
    for (int mi = 0; mi < 4; mi++)
#pragma unroll
      for (int ni = 0; ni < 4; ni++)
        acc[mi][ni] = __builtin_amdgcn_mfma_f32_16x16x32_bf16(afr[mi], bfr[ni], acc[mi][ni], 0, 0, 0);
    __builtin_amdgcn_s_setprio(0);
    __builtin_amdgcn_s_barrier();
    // ---- phase 3
#pragma unroll
    for (int mi = 0; mi < 4; mi++) afr[mi] = ldsfrag(Acur + 16384, rA + 64 + mi * 16, g);
    if (kt + 2 < NT) stage_half(Bcur, Bg, K, (kt + 2) * 64, tid);
    __builtin_amdgcn_s_barrier();
    asm volatile("s_waitcnt lgkmcnt(0)" ::: "memory");
    __builtin_amdgcn_s_setprio(1);
#pragma unroll
    for (int mi = 0; mi < 4; mi++)
#pragma unroll
      for (int ni = 0; ni < 4; ni++)
        acc[4 + mi][ni] = __builtin_amdgcn_mfma_f32_16x16x32_bf16(afr[mi], bfr[ni], acc[4 + mi][ni], 0, 0, 0);
    __builtin_amdgcn_s_setprio(0);
    if (kt < NT - 1) {
      if (kt + 2 < NT) asm volatile("s_waitcnt vmcnt(8)" ::: "memory");
      else             asm volatile("s_waitcnt vmcnt(4)" ::: "memory");
    }
    __builtin_amdgcn_s_barrier();
  }
#pragma unroll
  for (int mi = 0; mi < 8; mi++)
#pragma unroll
    for (int ni = 0; ni < 4; ni++) {
      int row0 = m0 + wm * 128 + mi * 16 + ((lane >> 4) << 2);
      int col = n0 + wn * 64 + ni * 16 + (lane & 15);
#pragma unroll
      for (int j = 0; j < 4; j++) {
        if constexpr (sizeof(CT) == 2)
          C[(size_t)(row0 + j) * N + col] = f2bf(acc[mi][ni][j]);
        else
          C[(size_t)(row0 + j) * N + col] = acc[mi][ni][j];
      }
    }
}

// ---------------------------------------------------------------- 128x128 bf16 GEMM (m97 structure)
template <typename CT>
__global__ __launch_bounds__(256) void gemm_bt(const u16t* __restrict__ A,
                                               const u16t* __restrict__ Bt,
                                               CT* __restrict__ C,
                                               int M, int N, int K) {
  __shared__ __align__(16) char As[128 * 64];
  __shared__ __align__(16) char Bs[128 * 64];
  int tid = threadIdx.x;
  int lane = tid & 63;
  int w = tid >> 6;
  int cpx = gridDim.x >> 3;
  int wgid = ((int)blockIdx.x & 7) * cpx + ((int)blockIdx.x >> 3);
  int mtiles = M >> 7;
  int bm = wgid % mtiles;
  int bn = wgid / mtiles;
  int m0 = bm << 7, n0 = bn << 7;
  int wr = (w >> 1) * 64, wc = (w & 1) * 64;

  const f32x4 fz = {0.f, 0.f, 0.f, 0.f};
  f32x4 acc[4][4];
#pragma unroll
  for (int i = 0; i < 4; i++)
#pragma unroll
    for (int j = 0; j < 4; j++) acc[i][j] = fz;

  for (int k0 = 0; k0 < K; k0 += 32) {
    __syncthreads();
#pragma unroll
    for (int i = 0; i < 2; i++) {
      int idx = i * 256 + tid;
      int r = idx >> 2, c = idx & 3;
      int csrc = c ^ ((r >> 1) & 3);
      gload_lds16(A + (size_t)(m0 + r) * K + k0 + csrc * 8, As + idx * 16);
      gload_lds16(Bt + (size_t)(n0 + r) * K + k0 + csrc * 8, Bs + idx * 16);
    }
    __syncthreads();
    s16x8 af[4], bf[4];
    int g = lane >> 4;
#pragma unroll
    for (int mi = 0; mi < 4; mi++) {
      int r = wr + mi * 16 + (lane & 15);
      af[mi] = *(const s16x8*)(As + r * 64 + ((g ^ ((r >> 1) & 3)) << 4));
    }
#pragma unroll
    for (int ni = 0; ni < 4; ni++) {
      int r = wc + ni * 16 + (lane & 15);
      bf[ni] = *(const s16x8*)(Bs + r * 64 + ((g ^ ((r >> 1) & 3)) << 4));
    }
#pragma unroll
    for (int mi = 0; mi < 4; mi++)
#pragma unroll
      for (int ni = 0; ni < 4; ni++)
        acc[mi][ni] = __builtin_amdgcn_mfma_f32_16x16x32_bf16(af[mi], bf[ni], acc[mi][ni], 0, 0, 0);
  }
#pragma unroll
  for (int mi = 0; mi < 4; mi++)
#pragma unroll
    for (int ni = 0; ni < 4; ni++) {
      int row0 = m0 + wr + mi * 16 + ((lane >> 4) << 2);
      int col = n0 + wc + ni * 16 + (lane & 15);
#pragma unroll
      for (int j = 0; j < 4; j++) {
        if constexpr (sizeof(CT) == 2)
          C[(size_t)(row0 + j) * N + col] = f2bf(acc[mi][ni][j]);
        else
          C[(size_t)(row0 + j) * N + col] = acc[mi][ni][j];
      }
    }
}

// ------------------------------------------------- fused RMSNorm + RoPE for Q and K
__global__ __launch_bounds__(256) void qk_norm_rope(const u16t* __restrict__ Cqkv,
                                                    const float* __restrict__ rope,
                                                    const float* __restrict__ qw,
                                                    const float* __restrict__ kw,
                                                    u16t* __restrict__ Qb,   // (B,H,S,D)
                                                    u16t* __restrict__ Kb,   // (B,KV,S,D)
                                                    u16t* __restrict__ Gs,   // (B,S,H*D)
                                                    float* __restrict__ present) {
  int wid = blockIdx.x * 4 + (threadIdx.x >> 6);
  int lane = threadIdx.x & 63;
  const int NQ = BB * SS * HH; // 65536
  if (wid < NQ) {
    int b = wid >> 15;          // S*H = 32768
    int rem = wid & 32767;
    int s = rem >> 4, h = rem & 15;
    const u16t* base = Cqkv + (size_t)(b * SS + s) * NQKV + h * 256;
    float xlo = bf2f(base[lane]), xhi = bf2f(base[64 + lane]);
    float ss = xlo * xlo + xhi * xhi;
    ss += __shfl_xor(ss, 1);  ss += __shfl_xor(ss, 2);  ss += __shfl_xor(ss, 4);
    ss += __shfl_xor(ss, 8);  ss += __shfl_xor(ss, 16); ss += __shfl_xor(ss, 32);
    float r = rsqrtf(ss * (1.f / 128.f) + 1e-6f);
    float qlo = xlo * r * (1.f + qw[lane]);
    float qhi = xhi * r * (1.f + qw[64 + lane]);
    const float* cs = rope + (size_t)s * 256;
    float clo = cs[lane], chi = cs[64 + lane];
    float slo = cs[128 + lane], shi = cs[192 + lane];
    // 1/sqrt(128) * log2(e): scores land in log2 units -> exp2 in attention
    const float SC = 0.08838834764831845f * 1.4426950408889634f;
    float olo = (qlo * clo - qhi * slo) * SC;
    float ohi = (qhi * chi + qlo * shi) * SC;
    size_t qoff = (((size_t)b * HH + h) * SS + s) * DD;
    Qb[qoff + lane] = f2bf(olo);
    Qb[qoff + 64 + lane] = f2bf(ohi);
    float glo = bf2f(base[128 + lane]), ghi = bf2f(base[192 + lane]);
    size_t goff = ((size_t)(b * SS + s)) * (HH * DD) + h * DD;
    Gs[goff + lane] = f2bf(1.f / (1.f + __expf(-glo)));
    Gs[goff + 64 + lane] = f2bf(1.f / (1.f + __expf(-ghi)));
  } else {
    int wid2 = wid - NQ;        // (b, s, kv): per b = S*KV = 8192
    int b = wid2 >> 13;
    int rem = wid2 & 8191;
    int s = rem >> 2, kv = rem & 3;
    const u16t* base = Cqkv + (size_t)(b * SS + s) * NQKV + 4096 + kv * 128;
    float xlo = bf2f(base[lane]), xhi = bf2f(base[64 + lane]);
    float ss = xlo * xlo + xhi * xhi;
    ss += __shfl_xor(ss, 1);  ss += __shfl_xor(ss, 2);  ss += __shfl_xor(ss, 4);
    ss += __shfl_xor(ss, 8);  ss += __shfl_xor(ss, 16); ss += __shfl_xor(ss, 32);
    float r = rsqrtf(ss * (1.f / 128.f) + 1e-6f);
    float klo = xlo * r * (1.f + kw[lane]);
    float khi = xhi * r * (1.f + kw[64 + lane]);
    const float* cs = rope + (size_t)s * 256;
    float clo = cs[lane], chi = cs[64 + lane];
    float slo = cs[128 + lane], shi = cs[192 + lane];
    float olo = klo * clo - khi * slo;
    float ohi = khi * chi + klo * shi;
    size_t koff = (((size_t)b * KVH + kv) * SS + s) * DD;
    Kb[koff + lane] = f2bf(olo);
    Kb[koff + 64 + lane] = f2bf(ohi);
    size_t poff = (((size_t)(b * 2 * KVH + kv)) * SS + s) * DD;
    present[poff + lane] = olo;
    present[poff + 64 + lane] = ohi;
  }
}

// ------------------------------------------------- V: present write + V^T bf16 (B,KV,D,S)
__global__ __launch_bounds__(256) void v_write(const u16t* __restrict__ Cqkv,
                                               float* __restrict__ present,
                                               u16t* __restrict__ Vtb) {
  __shared__ float lds[128 * 65];
  int t = threadIdx.x;
  int b = blockIdx.x >> 7;
  int kv = (blockIdx.x >> 5) & 3;
  int s0 = (blockIdx.x & 31) << 6;
#pragma unroll
  for (int i = 0; i < 32; i++) {
    int idx = i * 256 + t;
    int sp = idx >> 7, d = idx & 127;
    float v = bf2f(Cqkv[(size_t)(b * SS + s0 + sp) * NQKV + 4608 + kv * 128 + d]);
    present[(((size_t)(b * 2 * KVH + KVH + kv)) * SS + s0 + sp) * DD + d] = v;
    lds[d * 65 + sp] = v;
  }
  __syncthreads();
#pragma unroll
  for (int i = 0; i < 8; i++) {
    int d = i * 16 + (t >> 4);
    int sp = (t & 15) * 4;
    s16x4 pk;
    pk[0] = (short)f2bf(lds[d * 65 + sp + 0]);
    pk[1] = (short)f2bf(lds[d * 65 + sp + 1]);
    pk[2] = (short)f2bf(lds[d * 65 + sp + 2]);
    pk[3] = (short)f2bf(lds[d * 65 + sp + 3]);
    *(s16x4*)(Vtb + ((size_t)(b * KVH + kv) * DD + d) * SS + s0 + sp) = pk;
  }
}

// ---------------------------------------------------------------- flash attention v4
// Paired q-tiles + K/V double-buffer (round-6 schedule) with SWAPPED QK^T:
// accs = mfma(K, Q) -> lane holds P^T values for q = lane&15, k = ni*16+g*4+j.
// Softmax fully per-lane (scalar mrun/lrun) + 2 shuffles; P packed to bf16 via
// v_cvt_pk_bf16_f32 and stored as u32 to a [q][k] granule-XOR LDS layout
// (32 banks x 2 lanes per store = conflict-free); PV A-frag reads 16B aligned.
// Scores are pre-scaled by log2(e)/sqrt(D) -> exp2 everywhere.
__global__ __launch_bounds__(256) void attn_kernel(const u16t* __restrict__ Qb,   // (B,H,S,D) pre-scaled
                                                   const u16t* __restrict__ Kb,   // (B,KV,S,D)
                                                   const u16t* __restrict__ Vtb,  // (B,KV,D,S)
                                                   const u16t* __restrict__ Gs,   // (B,S,H*D)
                                                   u16t* __restrict__ AttG) {     // (B,S,H*D)
  __shared__ __align__(16) char Ks[2][16384];   // 64 rows x 256B, chunk xor (r&7)
  __shared__ __align__(16) char Vs[2][16384];   // V^T: 128 rows x 128B, chunk xor (d&7)
  __shared__ __align__(16) char Ps[4 * 2048];   // per-wave P: [q:16][k-granule xor (q&7)] 128B rows

  int tid = threadIdx.x, lane = tid & 63, w = tid >> 6;
  int x = blockIdx.x & 7;          // XCD grouping: each XCD owns one (b,kv)
  int b = x >> 2, kv = x & 3;
  int rr = blockIdx.x >> 3;        // 0..63
  int h = kv * 4 + (rr & 3);
  int p = rr >> 2;                 // 0..15: pair {31-p, p}

  const u16t* Kbase = Kb + (((size_t)(b * KVH + kv)) * SS) * DD;
  const u16t* Vbase = Vtb + (((size_t)(b * KVH + kv)) * DD) * SS;

  auto stageK = [&](int kt, int buf) {
#pragma unroll
    for (int i = 0; i < 4; i++) {
      int idx = i * 256 + tid;
      int r_ = idx >> 4, c_ = idx & 15;
      gload_lds16(Kbase + (size_t)(kt * 64 + r_) * DD + (c_ ^ (r_ & 7)) * 8, Ks[buf] + idx * 16);
    }
  };
  auto stageV = [&](int kt, int buf) {
#pragma unroll
    for (int i = 0; i < 4; i++) {
      int idx = i * 256 + tid;
      int r_ = idx >> 3, c_ = idx & 7;
      gload_lds16(Vbase + (size_t)r_ * SS + kt * 64 + (c_ ^ (r_ & 7)) * 8, Vs[buf] + idx * 16);
    }
  };

  const f32x4 fz = {0.f, 0.f, 0.f, 0.f};
  int g = lane >> 4;
  int q15 = lane & 15;
  int q7 = q15 & 7;
  char* pq = Ps + w * 2048 + q15 * 128;   // this lane's q-row in P
  int cur = 0;

  // prologue: stage tile 0 of segment 0 into buffer 0
  stageK(0, 0);
  stageV(0, 0);

  for (int seg = 0; seg < 2; seg++) {
    int qt = (seg == 0) ? (31 - p) : p;
    const u16t* Qbase = Qb + (((size_t)(b * HH + h)) * SS + qt * 64) * DD;
    s16x8 qf[4];
    {
      const u16t* qrow = Qbase + (size_t)(w * 16 + q15) * DD + g * 8;
#pragma unroll
      for (int ks = 0; ks < 4; ks++) qf[ks] = *(const s16x8*)(qrow + ks * 32);
    }
    f32x4 acco[8];
#pragma unroll
    for (int f = 0; f < 8; f++) acco[f] = fz;
    float mrun = -INFINITY, lrun = 0.f;

    if (seg == 0) {
      asm volatile("s_waitcnt vmcnt(0)" ::: "memory");
      __builtin_amdgcn_s_barrier();
    }

    for (int kt = 0; kt <= qt; kt++) {
      bool havenext = (kt < qt) || (seg == 0);
      if (havenext) {
        int nk = (kt < qt) ? (kt + 1) : 0;   // next tile, or seg1's tile 0
        stageK(nk, cur ^ 1);
        stageV(nk, cur ^ 1);
      }
      // ---- swapped QK^T from Ks[cur]: accs[ni][j] = S[q = lane&15][k = ni*16+g*4+j]
      f32x4 accs[4];
#pragma unroll
      for (int ni = 0; ni < 4; ni++) accs[ni] = fz;
#pragma unroll
      for (int ni = 0; ni < 4; ni++) {
        int r = ni * 16 + q15;
#pragma unroll
        for (int ks = 0; ks < 4; ks++) {
          int g2 = ks * 4 + g;
          s16x8 bfk = *(const s16x8*)(Ks[cur] + r * 256 + ((g2 ^ (r & 7)) << 4));
          accs[ni] = __builtin_amdgcn_mfma_f32_16x16x32_bf16(bfk, qf[ks], accs[ni], 0, 0, 0);
        }
      }
      if (kt == qt) {
        int ql = w * 16 + q15;
#pragma unroll
        for (int ni = 0; ni < 4; ni++)
#pragma unroll
          for (int j = 0; j < 4; j++) {
            int kl = ni * 16 + (g << 2) + j;
            if (kl > ql) accs[ni][j] = -1e30f;
          }
      }
      // ---- per-lane softmax (q = lane&15; 4 lanes/q combine via 2 shuffles)
      f32x4 m4 = fmax4(fmax4(accs[0], accs[1]), fmax4(accs[2], accs[3]));
      float mt = fmaxf(fmaxf(m4[0], m4[1]), fmaxf(m4[2], m4[3]));
      mt = fmaxf(mt, __shfl_xor(mt, 16));
      mt = fmaxf(mt, __shfl_xor(mt, 32));
      float mnew = fmaxf(mrun, mt);
      float alpha = __builtin_amdgcn_exp2f(mrun - mnew);
      mrun = mnew;
      float rs = 0.f;
#pragma unroll
      for (int ni = 0; ni < 4; ni++)
#pragma unroll
        for (int j = 0; j < 4; j++) {
          float pv = __builtin_amdgcn_exp2f(accs[ni][j] - mnew);
          accs[ni][j] = pv;
          rs += pv;
        }
      rs += __shfl_xor(rs, 16);
      rs += __shfl_xor(rs, 32);
      lrun = lrun * alpha + rs;
      // broadcast alpha to acco's q layout (rows q = g*4+j)
      float ar[4];
#pragma unroll
      for (int j = 0; j < 4; j++) ar[j] = __shfl(alpha, (g << 2) + j);
#pragma unroll
      for (int f = 0; f < 8; f++)
#pragma unroll
        for (int j = 0; j < 4; j++) acco[f][j] *= ar[j];

      // ---- P pack (bf16 pairs along k) -> conflict-free u32 LDS stores
#pragma unroll
      for (int ni = 0; ni < 4; ni++)
#pragma unroll
        for (int jj = 0; jj < 2; jj++) {
          unsigned pk32 = cvtpk_bf16(accs[ni][2 * jj], accs[ni][2 * jj + 1]);
          int gr = ni * 2 + (g >> 1);             // k granule (8 u16)
          int off = ((gr ^ q7) << 4) + ((g & 1) << 3) + (jj << 2);
          *(unsigned*)(pq + off) = pk32;
        }
      // ---- PV from Vs[cur]
#pragma unroll
      for (int ks2 = 0; ks2 < 2; ks2++) {
        s16x8 pa = *(const s16x8*)(pq + (((ks2 * 4 + g) ^ q7) << 4));
#pragma unroll
        for (int f = 0; f < 8; f++) {
          int d = f * 16 + q15;
          s16x8 vf = *(const s16x8*)(Vs[cur] + d * 128 + (((ks2 * 4 + g) ^ (d & 7)) << 4));
          acco[f] = __builtin_amdgcn_mfma_f32_16x16x32_bf16(pa, vf, acco[f], 0, 0, 0);
        }
      }
      // ---- tile boundary: next tile staged, current reads done
      if (havenext) {
        asm volatile("s_waitcnt vmcnt(0)" ::: "memory");
        __builtin_amdgcn_s_barrier();
        cur ^= 1;
      }
    }
    // ---- segment epilogue: gate + store (lrun broadcast to acco layout)
    float lr[4];
#pragma unroll
    for (int j = 0; j < 4; j++) lr[j] = __shfl(lrun, (g << 2) + j);
#pragma unroll
    for (int f = 0; f < 8; f++) {
      int d = f * 16 + q15;
#pragma unroll
      for (int j = 0; j < 4; j++) {
        int srow = qt * 64 + w * 16 + (g << 2) + j;
        float o = acco[f][j] / lr[j];
        size_t off = ((size_t)b * SS + srow) * (HH * DD) + h * DD + d;
        float gt = bf2f(Gs[off]);
        AttG[off] = f2bf(o * gt);
      }
    }
  }
}

// ---------------------------------------------------------------- launcher
extern "C" void kernel_launch(void* const* d_in, const int* in_sizes, int n_in,
                              void* d_out, int out_size, void* d_ws, size_t ws_size,
                              hipStream_t stream) {
  const float* hidden = (const float*)d_in[0];
  const float* rope   = (const float*)d_in[2];
  const float* Wq     = (const float*)d_in[5];
  const float* Wk     = (const float*)d_in[6];
  const float* Wv     = (const float*)d_in[7];
  const float* Wo     = (const float*)d_in[8];
  const float* qw     = (const float*)d_in[9];
  const float* kw     = (const float*)d_in[10];
  float* out = (float*)d_out;
  float* present = out + (size_t)BB * SS * HIDD; // 8,388,608

  char* ws = (char*)d_ws;
  u16t* Xb    = (u16t*)(ws);                              // 4096x2048 bf16   16.78MB
  u16t* Wt    = (u16t*)(ws + 16777216);                   // 5120x2048 bf16   20.97MB
  u16t* Wot   = (u16t*)(ws + 37748736);                   // 2048x2048 bf16    8.39MB
  u16t* Cqkv  = (u16t*)(ws + 46137344);                   // 4096x5120 bf16   41.94MB
  u16t* Qb    = (u16t*)(ws + 88080384);                   // (B,H,S,D) bf16   16.78MB
  u16t* Kb    = (u16t*)(ws + 104857600);                  // (B,KV,S,D) bf16   4.19MB
  u16t* Vtb   = (u16t*)(ws + 109051904);                  // (B,KV,D,S) bf16   4.19MB
  u16t* Gs    = (u16t*)(ws + 113246208);                  // (B,S,H*D) bf16   16.78MB
  u16t* AttG  = Xb;  // alias: Xb dead after QKV GEMM; AttG written by attention

  (void)hipFuncSetAttribute(reinterpret_cast<const void*>(gemm8<u16t>),
                            hipFuncAttributeMaxDynamicSharedMemorySize, 131072);

  // 1. cast hidden -> bf16
  cast_x<<<8192, 256, 0, stream>>>(hidden, Xb);
  // 2. transpose-cast weights into B^T layout
  transpose_cast<<<(4096 / 64) * 32, 256, 0, stream>>>(Wq, Wt, 4096);
  transpose_cast<<<(512 / 64) * 32, 256, 0, stream>>>(Wk, Wt + (size_t)4096 * HIDD, 512);
  transpose_cast<<<(512 / 64) * 32, 256, 0, stream>>>(Wv, Wt + (size_t)4608 * HIDD, 512);
  transpose_cast<<<(2048 / 64) * 32, 256, 0, stream>>>(Wo, Wot, 2048);
  // 3a. Q projection (N=4096): 256^2 8-phase, grid 16x16 = 256 = exactly 1 block/CU
  gemm8<u16t><<<(MM / 256) * (4096 / 256), 512, 131072, stream>>>(Xb, Wt, Cqkv, MM, NQKV, HIDD);
  // 3b. K+V projection (N=1024): 128^2 m97, grid 32x8 = 256 = exactly 1 block/CU
  gemm_bt<u16t><<<(MM / 128) * (1024 / 128), 256, 0, stream>>>(
      Xb, Wt + (size_t)4096 * HIDD, Cqkv + 4096, MM, NQKV, HIDD);
  // 4. Q/K norm+rope (+present K, +sigmoid gate); V writer (+present V, +V^T)
  qk_norm_rope<<<(BB * SS * (HH + KVH)) / 4, 256, 0, stream>>>(Cqkv, rope, qw, kw, Qb, Kb, Gs, present);
  v_write<<<BB * KVH * (SS / 64), 256, 0, stream>>>(Cqkv, present, Vtb);
  // 5. flash attention v4: swapped QK^T + in-register softmax
  attn_kernel<<<BB * HH * (SS / 128), 256, 0, stream>>>(Qb, Kb, Vtb, Gs, AttG);
  // 6. output projection -> d_out: 128^2 m97, grid 32x16 = 512
  gemm_bt<float><<<(MM / 128) * (HIDD / 128), 256, 0, stream>>>(AttG, Wot, out, MM, HIDD, HIDD);
}

// Round 10
// 288.954 us; speedup vs baseline: 1.1938x; 1.0103x over previous
//
#include <hip/hip_runtime.h>
#include <hip/hip_bf16.h>
#include <cstdint>
#include <cstddef>

// Problem constants
#define BB   2
#define SS   2048
#define HIDD 2048
#define HH   16
#define KVH  4
#define DD   128
#define NQKV 5120   // H*2*D + KV*D + KV*D = 4096 + 512 + 512
#define MM   4096   // B*S

typedef unsigned short u16t;
typedef __attribute__((ext_vector_type(8))) short s16x8;
typedef __attribute__((ext_vector_type(4))) short s16x4;
typedef __attribute__((ext_vector_type(4))) float f32x4;

__device__ __forceinline__ u16t f2bf(float f) {
  unsigned u = __float_as_uint(f);
  u += 0x7fffu + ((u >> 16) & 1u);
  return (u16t)(u >> 16);
}
__device__ __forceinline__ float bf2f(u16t h) {
  return __uint_as_float(((unsigned)h) << 16);
}
__device__ __forceinline__ void gload_lds16(const void* g, void* l) {
  __builtin_amdgcn_global_load_lds(
      (const __attribute__((address_space(1))) unsigned int*)g,
      (__attribute__((address_space(3))) unsigned int*)l, 16, 0, 0);
}
__device__ __forceinline__ unsigned cvtpk_bf16(float lo, float hi) {
  unsigned r;
  asm("v_cvt_pk_bf16_f32 %0, %1, %2" : "=v"(r) : "v"(lo), "v"(hi));
  return r;
}
__device__ __forceinline__ f32x4 fmax4(f32x4 a, f32x4 b) {
  f32x4 r;
  r[0] = fmaxf(a[0], b[0]); r[1] = fmaxf(a[1], b[1]);
  r[2] = fmaxf(a[2], b[2]); r[3] = fmaxf(a[3], b[3]);
  return r;
}

// ----------------------------------------- fused prep: cast hidden + transpose-cast all weights
// blocks [0,8192): cast hidden f32 -> bf16 (4 elem/thread)
// blocks [8192, 8192+3584): 64x64 transpose-cast tiles of Wq/Wk/Wv/Wo
__global__ __launch_bounds__(256) void prep_all(const float* __restrict__ hidden,
                                                const float* __restrict__ Wq,
                                                const float* __restrict__ Wk,
                                                const float* __restrict__ Wv,
                                                const float* __restrict__ Wo,
                                                u16t* __restrict__ Xb,
                                                u16t* __restrict__ Wt,
                                                u16t* __restrict__ Wot) {
  __shared__ float lds[64 * 65];
  int bid = blockIdx.x;
  int t = threadIdx.x;
  if (bid < 8192) {
    size_t i = ((size_t)bid * 256 + t) * 4;
    f32x4 v = *(const f32x4*)(hidden + i);
    s16x4 o;
    o[0] = (short)f2bf(v[0]); o[1] = (short)f2bf(v[1]);
    o[2] = (short)f2bf(v[2]); o[3] = (short)f2bf(v[3]);
    *(s16x4*)(Xb + i) = o;
    return;
  }
  bid -= 8192;
  const float* src; u16t* dst; int N;
  if (bid < 2048)      { src = Wq; dst = Wt;                         N = 4096; }
  else if (bid < 2304) { src = Wk; dst = Wt + (size_t)4096 * HIDD;   N = 512;  bid -= 2048; }
  else if (bid < 2560) { src = Wv; dst = Wt + (size_t)4608 * HIDD;   N = 512;  bid -= 2304; }
  else                 { src = Wo; dst = Wot;                        N = 2048; bid -= 2560; }
  const int ktiles = HIDD / 64; // 32
  int n0 = (bid / ktiles) << 6;
  int k0 = (bid % ktiles) << 6;
#pragma unroll
  for (int i = 0; i < 16; i++) {
    int idx = i * 256 + t;
    int r = idx >> 6, c = idx & 63;
    lds[c * 65 + r] = src[(size_t)(k0 + r) * N + n0 + c];
  }
  __syncthreads();
#pragma unroll
  for (int i = 0; i < 16; i++) {
    int idx = i * 256 + t;
    int rr = idx >> 6, kk = idx & 63;
    dst[(size_t)(n0 + rr) * HIDD + k0 + kk] = f2bf(lds[rr * 65 + kk]);
  }
}

// ---------------------------------------------------------------- 256x256 8-phase bf16 GEMM
__device__ __forceinline__ s16x8 ldsfrag(const char* half, int r, int g) {
  return *(const s16x8*)(half + r * 64 + ((g ^ ((r >> 1) & 3)) << 4));
}
__device__ __forceinline__ void stage_half(char* ldsbase, const u16t* gbase,
                                           int K, int kcol, int tid) {
#pragma unroll
  for (int i = 0; i < 2; i++) {
    int o16 = i * 512 + tid;
    int r = o16 >> 2;
    int cs = (o16 & 3) ^ ((r >> 1) & 3);
    gload_lds16(gbase + (size_t)r * K + kcol + cs * 8, ldsbase + o16 * 16);
  }
}

template <typename CT>
__global__ __launch_bounds__(512, 2) void gemm8(const u16t* __restrict__ A,
                                                const u16t* __restrict__ Bt,
                                                CT* __restrict__ C,
                                                int M, int N, int K) {
  extern __shared__ __align__(16) char lds[];
  char* As = lds;           // [slot:32768][kk:16384]
  char* Bs = lds + 65536;
  int tid = threadIdx.x, lane = tid & 63, w = tid >> 6;
  int wm = w >> 2, wn = w & 3;
  int cpx = gridDim.x >> 3;                       // grid % 8 == 0
  int wgid = (blockIdx.x & 7) * cpx + (blockIdx.x >> 3);
  int bm = wgid & 15, bn = wgid >> 4;             // M/256 == 16
  int m0 = bm << 8, n0 = bn << 8;
  const u16t* Ag = A + (size_t)m0 * K;
  const u16t* Bg = Bt + (size_t)n0 * K;
  const int NT = K >> 6;

  stage_half(As, Ag, K, 0, tid);
  stage_half(Bs, Bg, K, 0, tid);
  stage_half(As + 16384, Ag, K, 32, tid);
  stage_half(Bs + 16384, Bg, K, 32, tid);
  stage_half(As + 32768, Ag, K, 64, tid);
  stage_half(Bs + 32768, Bg, K, 64, tid);
  asm volatile("s_waitcnt vmcnt(8)" ::: "memory");
  __builtin_amdgcn_s_barrier();

  const f32x4 fz = {0.f, 0.f, 0.f, 0.f};
  f32x4 acc[8][4];
#pragma unroll
  for (int i = 0; i < 8; i++)
#pragma unroll
    for (int j = 0; j < 4; j++) acc[i][j] = fz;
  s16x8 afr[4], bfr[4];
  int g = lane >> 4;
  int rA = (lane & 15) + wm * 128;
  int rB = (lane & 15) + wn * 64;

  for (int kt = 0; kt < NT; kt++) {
    int cur = kt & 1;
    char* Acur = As + cur * 32768;
    char* Bcur = Bs + cur * 32768;
    char* Anxt = As + (cur ^ 1) * 32768;
    char* Bnxt = Bs + (cur ^ 1) * 32768;
    // ---- phase 0
#pragma unroll
    for (int ni = 0; ni < 4; ni++) bfr[ni] = ldsfrag(Bcur, rB + ni * 16, g);
#pragma unroll
    for (int mi = 0; mi < 4; mi++) afr[mi] = ldsfrag(Acur, rA + mi * 16, g);
    if (kt + 1 < NT) stage_half(Anxt + 16384, Ag, K, (kt + 1) * 64 + 32, tid);
    __builtin_amdgcn_s_barrier();
    asm volatile("s_waitcnt lgkmcnt(0)" ::: "memory");
    __builtin_amdgcn_s_setprio(1);
#pragma unroll
    for (int mi = 0; mi < 4; mi++)
#pragma unroll
      for (int ni = 0; ni < 4; ni++)
        acc[mi][ni] = __builtin_amdgcn_mfma_f32_16x16x32_bf16(afr[mi], bfr[ni], acc[mi][ni], 0, 0, 0);
    __builtin_amdgcn_s_setprio(0);
    __builtin_amdgcn_s_barrier();
    // ---- phase 1
#pragma unroll
    for (int mi = 0; mi < 4; mi++) afr[mi] = ldsfrag(Acur, rA + 64 + mi * 16, g);
    if (kt + 1 < NT) stage_half(Bnxt + 16384, Bg, K, (kt + 1) * 64 + 32, tid);
    __builtin_amdgcn_s_barrier();
    asm volatile("s_waitcnt lgkmcnt(0)" ::: "memory");
    __builtin_amdgcn_s_setprio(1);
#pragma unroll
    for (int mi = 0; mi < 4; mi++)
#pragma unroll
      for (int ni = 0; ni < 4; ni++)
        acc[4 + mi][ni] = __builtin_amdgcn_mfma_f32_16x16x32_bf16(afr[mi], bfr[ni], acc[4 + mi][ni], 0, 0, 0);
    __builtin_amdgcn_s_setprio(0);
    if (kt + 1 < NT) asm volatile("s_waitcnt vmcnt(8)" ::: "memory");
    else             asm volatile("s_waitcnt vmcnt(0)" ::: "memory");
    __builtin_amdgcn_s_barrier();
    // ---- phase 2
#pragma unroll
    for (int ni = 0; ni < 4; ni++) bfr[ni] = ldsfrag(Bcur + 16384, rB + ni * 16, g);
#pragma unroll
    for (int mi = 0; mi < 4; mi++) afr[mi] = ldsfrag(Acur + 16384, rA + mi * 16, g);
    if (kt + 2 < NT) stage_half(Acur, Ag, K, (kt + 2) * 64, tid);
    __builtin_amdgcn_s_barrier();
    asm volatile("s_waitcnt lgkmcnt(0)" ::: "memory");
    __builtin_amdgcn_s_setprio(1);
#pragma unroll
    for (int mi = 0; mi < 4; mi++)
#pragma unroll
      for (int ni = 0; ni < 4; ni++)
        acc[mi][ni] = __builtin_amdgcn_mfma_f32_16x16x32_bf16(afr[mi], bfr[ni], acc[mi][ni], 0, 0, 0);
    __builtin_amdgcn_s_setprio(0);
    __builtin_amdgcn_s_barrier();
    // ---- phase 3
#pragma unroll
    for (int mi = 0; mi < 4; mi++) afr[mi] = ldsfrag(Acur + 16384, rA + 64 + mi * 16, g);
    if (kt + 2 < NT) stage_half(Bcur, Bg, K, (kt + 2) * 64, tid);
    __builtin_amdgcn_s_barrier();
    asm volatile("s_waitcnt lgkmcnt(0)" ::: "memory");
    __builtin_amdgcn_s_setprio(1);
#pragma unroll
    for (int mi = 0; mi < 4; mi++)
#pragma unroll
      for (int ni = 0; ni < 4; ni++)
        acc[4 + mi][ni] = __builtin_amdgcn_mfma_f32_16x16x32_bf16(afr[mi], bfr[ni], acc[4 + mi][ni], 0, 0, 0);
    __builtin_amdgcn_s_setprio(0);
    if (kt < NT - 1) {
      if (kt + 2 < NT) asm volatile("s_waitcnt vmcnt(8)" ::: "memory");
      else             asm volatile("s_waitcnt vmcnt(4)" ::: "memory");
    }
    __builtin_amdgcn_s_barrier();
  }
#pragma unroll
  for (int mi = 0; mi < 8; mi++)
#pragma unroll
    for (int ni = 0; ni < 4; ni++) {
      int row0 = m0 + wm * 128 + mi * 16 + ((lane >> 4) << 2);
      int col = n0 + wn * 64 + ni * 16 + (lane & 15);
#pragma unroll
      for (int j = 0; j < 4; j++) {
        if constexpr (sizeof(CT) == 2)
          C[(size_t)(row0 + j) * N + col] = f2bf(acc[mi][ni][j]);
        else
          C[(size_t)(row0 + j) * N + col] = acc[mi][ni][j];
      }
    }
}

// ---------------------------------------------------------------- 128x128 bf16 GEMM (m97 structure)
template <typename CT>
__global__ __launch_bounds__(256) void gemm_bt(const u16t* __restrict__ A,
                                               const u16t* __restrict__ Bt,
                                               CT* __restrict__ C,
                                               int M, int N, int K) {
  __shared__ __align__(16) char As[128 * 64];
  __shared__ __align__(16) char Bs[128 * 64];
  int tid = threadIdx.x;
  int lane = tid & 63;
  int w = tid >> 6;
  int cpx = gridDim.x >> 3;
  int wgid = ((int)blockIdx.x & 7) * cpx + ((int)blockIdx.x >> 3);
  int mtiles = M >> 7;
  int bm = wgid % mtiles;
  int bn = wgid / mtiles;
  int m0 = bm << 7, n0 = bn << 7;
  int wr = (w >> 1) * 64, wc = (w & 1) * 64;

  const f32x4 fz = {0.f, 0.f, 0.f, 0.f};
  f32x4 acc[4][4];
#pragma unroll
  for (int i = 0; i < 4; i++)
#pragma unroll
    for (int j = 0; j < 4; j++) acc[i][j] = fz;

  for (int k0 = 0; k0 < K; k0 += 32) {
    __syncthreads();
#pragma unroll
    for (int i = 0; i < 2; i++) {
      int idx = i * 256 + tid;
      int r = idx >> 2, c = idx & 3;
      int csrc = c ^ ((r >> 1) & 3);
      gload_lds16(A + (size_t)(m0 + r) * K + k0 + csrc * 8, As + idx * 16);
      gload_lds16(Bt + (size_t)(n0 + r) * K + k0 + csrc * 8, Bs + idx * 16);
    }
    __syncthreads();
    s16x8 af[4], bf[4];
    int g = lane >> 4;
#pragma unroll
    for (int mi = 0; mi < 4; mi++) {
      int r = wr + mi * 16 + (lane & 15);
      af[mi] = *(const s16x8*)(As + r * 64 + ((g ^ ((r >> 1) & 3)) << 4));
    }
#pragma unroll
    for (int ni = 0; ni < 4; ni++) {
      int r = wc + ni * 16 + (lane & 15);
      bf[ni] = *(const s16x8*)(Bs + r * 64 + ((g ^ ((r >> 1) & 3)) << 4));
    }
#pragma unroll
    for (int mi = 0; mi < 4; mi++)
#pragma unroll
      for (int ni = 0; ni < 4; ni++)
        acc[mi][ni] = __builtin_amdgcn_mfma_f32_16x16x32_bf16(af[mi], bf[ni], acc[mi][ni], 0, 0, 0);
  }
#pragma unroll
  for (int mi = 0; mi < 4; mi++)
#pragma unroll
    for (int ni = 0; ni < 4; ni++) {
      int row0 = m0 + wr + mi * 16 + ((lane >> 4) << 2);
      int col = n0 + wc + ni * 16 + (lane & 15);
#pragma unroll
      for (int j = 0; j < 4; j++) {
        if constexpr (sizeof(CT) == 2)
          C[(size_t)(row0 + j) * N + col] = f2bf(acc[mi][ni][j]);
        else
          C[(size_t)(row0 + j) * N + col] = acc[mi][ni][j];
      }
    }
}

// ------------------------------------------------- fused RMSNorm + RoPE for Q and K
__global__ __launch_bounds__(256) void qk_norm_rope(const u16t* __restrict__ Cqkv,
                                                    const float* __restrict__ rope,
                                                    const float* __restrict__ qw,
                                                    const float* __restrict__ kw,
                                                    u16t* __restrict__ Qb,   // (B,H,S,D)
                                                    u16t* __restrict__ Kb,   // (B,KV,S,D)
                                                    u16t* __restrict__ Gs,   // (B,S,H*D)
                                                    float* __restrict__ present) {
  int wid = blockIdx.x * 4 + (threadIdx.x >> 6);
  int lane = threadIdx.x & 63;
  const int NQ = BB * SS * HH; // 65536
  if (wid < NQ) {
    int b = wid >> 15;          // S*H = 32768
    int rem = wid & 32767;
    int s = rem >> 4, h = rem & 15;
    const u16t* base = Cqkv + (size_t)(b * SS + s) * NQKV + h * 256;
    float xlo = bf2f(base[lane]), xhi = bf2f(base[64 + lane]);
    float ss = xlo * xlo + xhi * xhi;
    ss += __shfl_xor(ss, 1);  ss += __shfl_xor(ss, 2);  ss += __shfl_xor(ss, 4);
    ss += __shfl_xor(ss, 8);  ss += __shfl_xor(ss, 16); ss += __shfl_xor(ss, 32);
    float r = rsqrtf(ss * (1.f / 128.f) + 1e-6f);
    float qlo = xlo * r * (1.f + qw[lane]);
    float qhi = xhi * r * (1.f + qw[64 + lane]);
    const float* cs = rope + (size_t)s * 256;
    float clo = cs[lane], chi = cs[64 + lane];
    float slo = cs[128 + lane], shi = cs[192 + lane];
    // 1/sqrt(128) * log2(e): scores land in log2 units -> exp2 in attention
    const float SC = 0.08838834764831845f * 1.4426950408889634f;
    float olo = (qlo * clo - qhi * slo) * SC;
    float ohi = (qhi * chi + qlo * shi) * SC;
    size_t qoff = (((size_t)b * HH + h) * SS + s) * DD;
    Qb[qoff + lane] = f2bf(olo);
    Qb[qoff + 64 + lane] = f2bf(ohi);
    float glo = bf2f(base[128 + lane]), ghi = bf2f(base[192 + lane]);
    size_t goff = ((size_t)(b * SS + s)) * (HH * DD) + h * DD;
    Gs[goff + lane] = f2bf(1.f / (1.f + __expf(-glo)));
    Gs[goff + 64 + lane] = f2bf(1.f / (1.f + __expf(-ghi)));
  } else {
    int wid2 = wid - NQ;        // (b, s, kv): per b = S*KV = 8192
    int b = wid2 >> 13;
    int rem = wid2 & 8191;
    int s = rem >> 2, kv = rem & 3;
    const u16t* base = Cqkv + (size_t)(b * SS + s) * NQKV + 4096 + kv * 128;
    float xlo = bf2f(base[lane]), xhi = bf2f(base[64 + lane]);
    float ss = xlo * xlo + xhi * xhi;
    ss += __shfl_xor(ss, 1);  ss += __shfl_xor(ss, 2);  ss += __shfl_xor(ss, 4);
    ss += __shfl_xor(ss, 8);  ss += __shfl_xor(ss, 16); ss += __shfl_xor(ss, 32);
    float r = rsqrtf(ss * (1.f / 128.f) + 1e-6f);
    float klo = xlo * r * (1.f + kw[lane]);
    float khi = xhi * r * (1.f + kw[64 + lane]);
    const float* cs = rope + (size_t)s * 256;
    float clo = cs[lane], chi = cs[64 + lane];
    float slo = cs[128 + lane], shi = cs[192 + lane];
    float olo = klo * clo - khi * slo;
    float ohi = khi * chi + klo * shi;
    size_t koff = (((size_t)b * KVH + kv) * SS + s) * DD;
    Kb[koff + lane] = f2bf(olo);
    Kb[koff + 64 + lane] = f2bf(ohi);
    size_t poff = (((size_t)(b * 2 * KVH + kv)) * SS + s) * DD;
    present[poff + lane] = olo;
    present[poff + 64 + lane] = ohi;
  }
}

// ------------------------------------------------- V: present write + V^T bf16 (B,KV,D,S)
__global__ __launch_bounds__(256) void v_write(const u16t* __restrict__ Cqkv,
                                               float* __restrict__ present,
                                               u16t* __restrict__ Vtb) {
  __shared__ float lds[128 * 65];
  int t = threadIdx.x;
  int b = blockIdx.x >> 7;
  int kv = (blockIdx.x >> 5) & 3;
  int s0 = (blockIdx.x & 31) << 6;
#pragma unroll
  for (int i = 0; i < 32; i++) {
    int idx = i * 256 + t;
    int sp = idx >> 7, d = idx & 127;
    float v = bf2f(Cqkv[(size_t)(b * SS + s0 + sp) * NQKV + 4608 + kv * 128 + d]);
    present[(((size_t)(b * 2 * KVH + KVH + kv)) * SS + s0 + sp) * DD + d] = v;
    lds[d * 65 + sp] = v;
  }
  __syncthreads();
#pragma unroll
  for (int i = 0; i < 8; i++) {
    int d = i * 16 + (t >> 4);
    int sp = (t & 15) * 4;
    s16x4 pk;
    pk[0] = (short)f2bf(lds[d * 65 + sp + 0]);
    pk[1] = (short)f2bf(lds[d * 65 + sp + 1]);
    pk[2] = (short)f2bf(lds[d * 65 + sp + 2]);
    pk[3] = (short)f2bf(lds[d * 65 + sp + 3]);
    *(s16x4*)(Vtb + ((size_t)(b * KVH + kv) * DD + d) * SS + s0 + sp) = pk;
  }
}

// ---------------------------------------------------------------- flash attention v4.1
// Paired q-tiles + K/V double-buffer, swapped QK^T in-register softmax.
// v4.1: P stores as ds_write_b64 (halves store bank-conflict cycles) and
// tree-structured row-sum (depth ~6 instead of 16-deep dependent chain).
__global__ __launch_bounds__(256) void attn_kernel(const u16t* __restrict__ Qb,   // (B,H,S,D) pre-scaled
                                                   const u16t* __restrict__ Kb,   // (B,KV,S,D)
                                                   const u16t* __restrict__ Vtb,  // (B,KV,D,S)
                                                   const u16t* __restrict__ Gs,   // (B,S,H*D)
                                                   u16t* __restrict__ AttG) {     // (B,S,H*D)
  __shared__ __align__(16) char Ks[2][16384];   // 64 rows x 256B, chunk xor (r&7)
  __shared__ __align__(16) char Vs[2][16384];   // V^T: 128 rows x 128B, chunk xor (d&7)
  __shared__ __align__(16) char Ps[4 * 2048];   // per-wave P: [q:16][k-granule xor (q&7)] 128B rows

  int tid = threadIdx.x, lane = tid & 63, w = tid >> 6;
  int x = blockIdx.x & 7;          // XCD grouping: each XCD owns one (b,kv)
  int b = x >> 2, kv = x & 3;
  int rr = blockIdx.x >> 3;        // 0..63
  int h = kv * 4 + (rr & 3);
  int p = rr >> 2;                 // 0..15: pair {31-p, p}

  const u16t* Kbase = Kb + (((size_t)(b * KVH + kv)) * SS) * DD;
  const u16t* Vbase = Vtb + (((size_t)(b * KVH + kv)) * DD) * SS;

  auto stageK = [&](int kt, int buf) {
#pragma unroll
    for (int i = 0; i < 4; i++) {
      int idx = i * 256 + tid;
      int r_ = idx >> 4, c_ = idx & 15;
      gload_lds16(Kbase + (size_t)(kt * 64 + r_) * DD + (c_ ^ (r_ & 7)) * 8, Ks[buf] + idx * 16);
    }
  };
  auto stageV = [&](int kt, int buf) {
#pragma unroll
    for (int i = 0; i < 4; i++) {
      int idx = i * 256 + tid;
      int r_ = idx >> 3, c_ = idx & 7;
      gload_lds16(Vbase + (size_t)r_ * SS + kt * 64 + (c_ ^ (r_ & 7)) * 8, Vs[buf] + idx * 16);
    }
  };

  const f32x4 fz = {0.f, 0.f, 0.f, 0.f};
  int g = lane >> 4;
  int q15 = lane & 15;
  int q7 = q15 & 7;
  char* pq = Ps + w * 2048 + q15 * 128;   // this lane's q-row in P
  int cur = 0;

  // prologue: stage tile 0 of segment 0 into buffer 0
  stageK(0, 0);
  stageV(0, 0);

  for (int seg = 0; seg < 2; seg++) {
    int qt = (seg == 0) ? (31 - p) : p;
    const u16t* Qbase = Qb + (((size_t)(b * HH + h)) * SS + qt * 64) * DD;
    s16x8 qf[4];
    {
      const u16t* qrow = Qbase + (size_t)(w * 16 + q15) * DD + g * 8;
#pragma unroll
      for (int ks = 0; ks < 4; ks++) qf[ks] = *(const s16x8*)(qrow + ks * 32);
    }
    f32x4 acco[8];
#pragma unroll
    for (int f = 0; f < 8; f++) acco[f] = fz;
    float mrun = -INFINITY, lrun = 0.f;

    if (seg == 0) {
      asm volatile("s_waitcnt vmcnt(0)" ::: "memory");
      __builtin_amdgcn_s_barrier();
    }

    for (int kt = 0; kt <= qt; kt++) {
      bool havenext = (kt < qt) || (seg == 0);
      if (havenext) {
        int nk = (kt < qt) ? (kt + 1) : 0;   // next tile, or seg1's tile 0
        stageK(nk, cur ^ 1);
        stageV(nk, cur ^ 1);
      }
      // ---- swapped QK^T from Ks[cur]: accs[ni][j] = S[q = lane&15][k = ni*16+g*4+j]
      f32x4 accs[4];
#pragma unroll
      for (int ni = 0; ni < 4; ni++) accs[ni] = fz;
#pragma unroll
      for (int ni = 0; ni < 4; ni++) {
        int r = ni * 16 + q15;
#pragma unroll
        for (int ks = 0; ks < 4; ks++) {
          int g2 = ks * 4 + g;
          s16x8 bfk = *(const s16x8*)(Ks[cur] + r * 256 + ((g2 ^ (r & 7)) << 4));
          accs[ni] = __builtin_amdgcn_mfma_f32_16x16x32_bf16(bfk, qf[ks], accs[ni], 0, 0, 0);
        }
      }
      if (kt == qt) {
        int ql = w * 16 + q15;
#pragma unroll
        for (int ni = 0; ni < 4; ni++)
#pragma unroll
          for (int j = 0; j < 4; j++) {
            int kl = ni * 16 + (g << 2) + j;
            if (kl > ql) accs[ni][j] = -1e30f;
          }
      }
      // ---- per-lane softmax (q = lane&15; 4 lanes/q combine via 2 shuffles)
      f32x4 m4 = fmax4(fmax4(accs[0], accs[1]), fmax4(accs[2], accs[3]));
      float mt = fmaxf(fmaxf(m4[0], m4[1]), fmaxf(m4[2], m4[3]));
      mt = fmaxf(mt, __shfl_xor(mt, 16));
      mt = fmaxf(mt, __shfl_xor(mt, 32));
      float mnew = fmaxf(mrun, mt);
      float alpha = __builtin_amdgcn_exp2f(mrun - mnew);
      mrun = mnew;
#pragma unroll
      for (int ni = 0; ni < 4; ni++)
#pragma unroll
        for (int j = 0; j < 4; j++)
          accs[ni][j] = __builtin_amdgcn_exp2f(accs[ni][j] - mnew);
      f32x4 s01 = accs[0] + accs[1];
      f32x4 s23 = accs[2] + accs[3];
      f32x4 s4 = s01 + s23;
      float rs = (s4[0] + s4[1]) + (s4[2] + s4[3]);
      rs += __shfl_xor(rs, 16);
      rs += __shfl_xor(rs, 32);
      lrun = lrun * alpha + rs;
      // broadcast alpha to acco's q layout (rows q = g*4+j)
      float ar[4];
#pragma unroll
      for (int j = 0; j < 4; j++) ar[j] = __shfl(alpha, (g << 2) + j);
#pragma unroll
      for (int f = 0; f < 8; f++)
#pragma unroll
        for (int j = 0; j < 4; j++) acco[f][j] *= ar[j];

      // ---- P pack (bf16 pairs along k) -> b64 LDS stores (halved conflicts)
#pragma unroll
      for (int ni = 0; ni < 4; ni++) {
        uint2 pk;
        pk.x = cvtpk_bf16(accs[ni][0], accs[ni][1]);
        pk.y = cvtpk_bf16(accs[ni][2], accs[ni][3]);
        int gr = ni * 2 + (g >> 1);             // k granule (8 u16)
        *(uint2*)(pq + ((gr ^ q7) << 4) + ((g & 1) << 3)) = pk;
      }
      // ---- PV from Vs[cur]
#pragma unroll
      for (int ks2 = 0; ks2 < 2; ks2++) {
        s16x8 pa = *(const s16x8*)(pq + (((ks2 * 4 + g) ^ q7) << 4));
#pragma unroll
        for (int f = 0; f < 8; f++) {
          int d = f * 16 + q15;
          s16x8 vf = *(const s16x8*)(Vs[cur] + d * 128 + (((ks2 * 4 + g) ^ (d & 7)) << 4));
          acco[f] = __builtin_amdgcn_mfma_f32_16x16x32_bf16(pa, vf, acco[f], 0, 0, 0);
        }
      }
      // ---- tile boundary: next tile staged, current reads done
      if (havenext) {
        asm volatile("s_waitcnt vmcnt(0)" ::: "memory");
        __builtin_amdgcn_s_barrier();
        cur ^= 1;
      }
    }
    // ---- segment epilogue: gate + store (lrun broadcast to acco layout)
    float lr[4];
#pragma unroll
    for (int j = 0; j < 4; j++) lr[j] = __shfl(lrun, (g << 2) + j);
#pragma unroll
    for (int f = 0; f < 8; f++) {
      int d = f * 16 + q15;
#pragma unroll
      for (int j = 0; j < 4; j++) {
        int srow = qt * 64 + w * 16 + (g << 2) + j;
        float o = acco[f][j] / lr[j];
        size_t off = ((size_t)b * SS + srow) * (HH * DD) + h * DD + d;
        float gt = bf2f(Gs[off]);
        AttG[off] = f2bf(o * gt);
      }
    }
  }
}

// ---------------------------------------------------------------- launcher
extern "C" void kernel_launch(void* const* d_in, const int* in_sizes, int n_in,
                              void* d_out, int out_size, void* d_ws, size_t ws_size,
                              hipStream_t stream) {
  const float* hidden = (const float*)d_in[0];
  const float* rope   = (const float*)d_in[2];
  const float* Wq     = (const float*)d_in[5];
  const float* Wk     = (const float*)d_in[6];
  const float* Wv     = (const float*)d_in[7];
  const float* Wo     = (const float*)d_in[8];
  const float* qw     = (const float*)d_in[9];
  const float* kw     = (const float*)d_in[10];
  float* out = (float*)d_out;
  float* present = out + (size_t)BB * SS * HIDD; // 8,388,608

  char* ws = (char*)d_ws;
  u16t* Xb    = (u16t*)(ws);                              // 4096x2048 bf16   16.78MB
  u16t* Wt    = (u16t*)(ws + 16777216);                   // 5120x2048 bf16   20.97MB
  u16t* Wot   = (u16t*)(ws + 37748736);                   // 2048x2048 bf16    8.39MB
  u16t* Cqkv  = (u16t*)(ws + 46137344);                   // 4096x5120 bf16   41.94MB
  u16t* Qb    = (u16t*)(ws + 88080384);                   // (B,H,S,D) bf16   16.78MB
  u16t* Kb    = (u16t*)(ws + 104857600);                  // (B,KV,S,D) bf16   4.19MB
  u16t* Vtb   = (u16t*)(ws + 109051904);                  // (B,KV,D,S) bf16   4.19MB
  u16t* Gs    = (u16t*)(ws + 113246208);                  // (B,S,H*D) bf16   16.78MB
  u16t* AttG  = Xb;  // alias: Xb dead after QKV GEMM; AttG written by attention

  (void)hipFuncSetAttribute(reinterpret_cast<const void*>(gemm8<u16t>),
                            hipFuncAttributeMaxDynamicSharedMemorySize, 131072);
  (void)hipFuncSetAttribute(reinterpret_cast<const void*>(gemm8<float>),
                            hipFuncAttributeMaxDynamicSharedMemorySize, 131072);

  // 1+2. fused prep: cast hidden + all weight transposes (one launch)
  prep_all<<<8192 + 3584, 256, 0, stream>>>(hidden, Wq, Wk, Wv, Wo, Xb, Wt, Wot);
  // 3a. Q projection (N=4096): 256^2 8-phase, grid 16x16 = 256 = exactly 1 block/CU
  gemm8<u16t><<<(MM / 256) * (4096 / 256), 512, 131072, stream>>>(Xb, Wt, Cqkv, MM, NQKV, HIDD);
  // 3b. K+V projection (N=1024): 128^2 m97, grid 32x8 = 256 = exactly 1 block/CU
  gemm_bt<u16t><<<(MM / 128) * (1024 / 128), 256, 0, stream>>>(
      Xb, Wt + (size_t)4096 * HIDD, Cqkv + 4096, MM, NQKV, HIDD);
  // 4. Q/K norm+rope (+present K, +sigmoid gate); V writer (+present V, +V^T)
  qk_norm_rope<<<(BB * SS * (HH + KVH)) / 4, 256, 0, stream>>>(Cqkv, rope, qw, kw, Qb, Kb, Gs, present);
  v_write<<<BB * KVH * (SS / 64), 256, 0, stream>>>(Cqkv, present, Vtb);
  // 5. flash attention v4.1: swapped QK^T + in-register softmax, b64 P-stores
  attn_kernel<<<BB * HH * (SS / 128), 256, 0, stream>>>(Qb, Kb, Vtb, Gs, AttG);
  // 6. output projection -> d_out: 256^2 8-phase, grid 16x8 = 128 (tail-free, ~6.1 TF/CU)
  gemm8<float><<<(MM / 256) * (HIDD / 256), 512, 131072, stream>>>(AttG, Wot, out, MM, HIDD, HIDD);
}

// Round 12
// 266.137 us; speedup vs baseline: 1.2961x; 1.0857x over previous
//
#include <hip/hip_runtime.h>
#include <hip/hip_bf16.h>
#include <cstdint>
#include <cstddef>

// Problem constants
#define BB   2
#define SS   2048
#define HIDD 2048
#define HH   16
#define KVH  4
#define DD   128
#define NQKV 5120   // H*2*D + KV*D + KV*D = 4096 + 512 + 512
#define MM   4096   // B*S

typedef unsigned short u16t;
typedef __attribute__((ext_vector_type(8))) short s16x8;
typedef __attribute__((ext_vector_type(4))) short s16x4;
typedef __attribute__((ext_vector_type(4))) float f32x4;

__device__ __forceinline__ u16t f2bf(float f) {
  unsigned u = __float_as_uint(f);
  u += 0x7fffu + ((u >> 16) & 1u);
  return (u16t)(u >> 16);
}
__device__ __forceinline__ float bf2f(u16t h) {
  return __uint_as_float(((unsigned)h) << 16);
}
__device__ __forceinline__ void gload_lds16(const void* g, void* l) {
  __builtin_amdgcn_global_load_lds(
      (const __attribute__((address_space(1))) unsigned int*)g,
      (__attribute__((address_space(3))) unsigned int*)l, 16, 0, 0);
}
__device__ __forceinline__ unsigned cvtpk_bf16(float lo, float hi) {
  unsigned r;
  asm("v_cvt_pk_bf16_f32 %0, %1, %2" : "=v"(r) : "v"(lo), "v"(hi));
  return r;
}
__device__ __forceinline__ f32x4 fmax4(f32x4 a, f32x4 b) {
  f32x4 r;
  r[0] = fmaxf(a[0], b[0]); r[1] = fmaxf(a[1], b[1]);
  r[2] = fmaxf(a[2], b[2]); r[3] = fmaxf(a[3], b[3]);
  return r;
}
// counted vmcnt via literal asm (compiler-ordering fence through "memory" clobber).
// Round-11 lesson: __builtin_amdgcn_s_waitcnt is NOT a memory fence -> race.
template <int N>
__device__ __forceinline__ void waitvm() {
  static_assert(N == 0 || N == 3 || N == 4 || N == 6 || N == 8, "add literal");
  if constexpr (N == 0)      asm volatile("s_waitcnt vmcnt(0)" ::: "memory");
  else if constexpr (N == 3) asm volatile("s_waitcnt vmcnt(3)" ::: "memory");
  else if constexpr (N == 4) asm volatile("s_waitcnt vmcnt(4)" ::: "memory");
  else if constexpr (N == 6) asm volatile("s_waitcnt vmcnt(6)" ::: "memory");
  else if constexpr (N == 8) asm volatile("s_waitcnt vmcnt(8)" ::: "memory");
}

// ----------------------------------------- fused prep: cast hidden + transpose-cast all weights
__global__ __launch_bounds__(256) void prep_all(const float* __restrict__ hidden,
                                                const float* __restrict__ Wq,
                                                const float* __restrict__ Wk,
                                                const float* __restrict__ Wv,
                                                const float* __restrict__ Wo,
                                                u16t* __restrict__ Xb,
                                                u16t* __restrict__ Wt,
                                                u16t* __restrict__ Wot) {
  __shared__ float lds[64 * 65];
  int bid = blockIdx.x;
  int t = threadIdx.x;
  if (bid < 8192) {
    size_t i = ((size_t)bid * 256 + t) * 4;
    f32x4 v = *(const f32x4*)(hidden + i);
    s16x4 o;
    o[0] = (short)f2bf(v[0]); o[1] = (short)f2bf(v[1]);
    o[2] = (short)f2bf(v[2]); o[3] = (short)f2bf(v[3]);
    *(s16x4*)(Xb + i) = o;
    return;
  }
  bid -= 8192;
  const float* src; u16t* dst; int N;
  if (bid < 2048)      { src = Wq; dst = Wt;                         N = 4096; }
  else if (bid < 2304) { src = Wk; dst = Wt + (size_t)4096 * HIDD;   N = 512;  bid -= 2048; }
  else if (bid < 2560) { src = Wv; dst = Wt + (size_t)4608 * HIDD;   N = 512;  bid -= 2304; }
  else                 { src = Wo; dst = Wot;                        N = 2048; bid -= 2560; }
  const int ktiles = HIDD / 64; // 32
  int n0 = (bid / ktiles) << 6;
  int k0 = (bid % ktiles) << 6;
#pragma unroll
  for (int i = 0; i < 16; i++) {
    int idx = i * 256 + t;
    int r = idx >> 6, c = idx & 63;
    lds[c * 65 + r] = src[(size_t)(k0 + r) * N + n0 + c];
  }
  __syncthreads();
#pragma unroll
  for (int i = 0; i < 16; i++) {
    int idx = i * 256 + t;
    int rr = idx >> 6, kk = idx & 63;
    dst[(size_t)(n0 + rr) * HIDD + k0 + kk] = f2bf(lds[rr * 65 + kk]);
  }
}

// ---------------------------------------------------------------- 256xBN 8-phase bf16 GEMM
// C(M x n, CT; row-stride N) = A(MxK) @ Bt(nxK)^T.  BK=64 (2 K-halves of 32).
// BN in {256,128}. grid = (M/256)*(n/BN); M/256 must be 16.
__device__ __forceinline__ s16x8 ldsfrag(const char* half, int r, int g) {
  return *(const s16x8*)(half + r * 64 + ((g ^ ((r >> 1) & 3)) << 4));
}
template <int NL>
__device__ __forceinline__ void stage_half(char* ldsbase, const u16t* gbase,
                                           int K, int kcol, int tid) {
#pragma unroll
  for (int i = 0; i < NL; i++) {
    int o16 = i * 512 + tid;
    int r = o16 >> 2;
    int cs = (o16 & 3) ^ ((r >> 1) & 3);
    gload_lds16(gbase + (size_t)r * K + kcol + cs * 8, ldsbase + o16 * 16);
  }
}

template <int BN, typename CT>
__global__ __launch_bounds__(512, 2) void gemm8(const u16t* __restrict__ A,
                                                const u16t* __restrict__ Bt,
                                                CT* __restrict__ C,
                                                int M, int N, int K) {
  constexpr int NLB = BN / 128;            // B-half loads/thread
  constexpr int AHALF = 16384, ASLOT = 32768;
  constexpr int BHALF = BN * 64, BSLOT = 2 * BHALF;
  constexpr int PAIR = 2 + NLB;            // loads per (A,B) half-tile pair
  constexpr int NI = BN / 64;              // B frags per wave
  extern __shared__ __align__(16) char lds[];
  char* As = lds;
  char* Bs = lds + 2 * ASLOT;
  int tid = threadIdx.x, lane = tid & 63, w = tid >> 6;
  int wm = w >> 2, wn = w & 3;
  int cpx = gridDim.x >> 3;                       // grid % 8 == 0
  int wgid = (blockIdx.x & 7) * cpx + (blockIdx.x >> 3);
  int bm = wgid & 15, bn = wgid >> 4;             // M/256 == 16
  int m0 = bm << 8, n0 = bn * BN;
  const u16t* Ag = A + (size_t)m0 * K;
  const u16t* Bg = Bt + (size_t)n0 * K;
  const int NT = K >> 6;

  stage_half<2>(As, Ag, K, 0, tid);
  stage_half<NLB>(Bs, Bg, K, 0, tid);
  stage_half<2>(As + AHALF, Ag, K, 32, tid);
  stage_half<NLB>(Bs + BHALF, Bg, K, 32, tid);
  stage_half<2>(As + ASLOT, Ag, K, 64, tid);
  stage_half<NLB>(Bs + BSLOT, Bg, K, 64, tid);
  waitvm<2 * PAIR>();
  __builtin_amdgcn_s_barrier();

  const f32x4 fz = {0.f, 0.f, 0.f, 0.f};
  f32x4 acc[8][NI];
#pragma unroll
  for (int i = 0; i < 8; i++)
#pragma unroll
    for (int j = 0; j < NI; j++) acc[i][j] = fz;
  s16x8 afr[4], bfr[NI];
  int g = lane >> 4;
  int rA = (lane & 15) + wm * 128;
  int rB = (lane & 15) + wn * (BN / 4);

  for (int kt = 0; kt < NT; kt++) {
    int cur = kt & 1;
    char* Acur = As + cur * ASLOT;
    char* Bcur = Bs + cur * BSLOT;
    char* Anxt = As + (cur ^ 1) * ASLOT;
    char* Bnxt = Bs + (cur ^ 1) * BSLOT;
    // ---- phase 0: (kk0, mh0); stage Ah1(kt+1)
#pragma unroll
    for (int ni = 0; ni < NI; ni++) bfr[ni] = ldsfrag(Bcur, rB + ni * 16, g);
#pragma unroll
    for (int mi = 0; mi < 4; mi++) afr[mi] = ldsfrag(Acur, rA + mi * 16, g);
    if (kt + 1 < NT) stage_half<2>(Anxt + AHALF, Ag, K, (kt + 1) * 64 + 32, tid);
    __builtin_amdgcn_s_barrier();
    asm volatile("s_waitcnt lgkmcnt(0)" ::: "memory");
    __builtin_amdgcn_s_setprio(1);
#pragma unroll
    for (int mi = 0; mi < 4; mi++)
#pragma unroll
      for (int ni = 0; ni < NI; ni++)
        acc[mi][ni] = __builtin_amdgcn_mfma_f32_16x16x32_bf16(afr[mi], bfr[ni], acc[mi][ni], 0, 0, 0);
    __builtin_amdgcn_s_setprio(0);
    __builtin_amdgcn_s_barrier();
    // ---- phase 1: (kk0, mh1); stage Bh1(kt+1); counted wait
#pragma unroll
    for (int mi = 0; mi < 4; mi++) afr[mi] = ldsfrag(Acur, rA + 64 + mi * 16, g);
    if (kt + 1 < NT) stage_half<NLB>(Bnxt + BHALF, Bg, K, (kt + 1) * 64 + 32, tid);
    __builtin_amdgcn_s_barrier();
    asm volatile("s_waitcnt lgkmcnt(0)" ::: "memory");
    __builtin_amdgcn_s_setprio(1);
#pragma unroll
    for (int mi = 0; mi < 4; mi++)
#pragma unroll
      for (int ni = 0; ni < NI; ni++)
        acc[4 + mi][ni] = __builtin_amdgcn_mfma_f32_16x16x32_bf16(afr[mi], bfr[ni], acc[4 + mi][ni], 0, 0, 0);
    __builtin_amdgcn_s_setprio(0);
    if (kt + 1 < NT) waitvm<2 * PAIR>();
    else             waitvm<0>();
    __builtin_amdgcn_s_barrier();
    // ---- phase 2: (kk1, mh0); stage Ah0(kt+2)
#pragma unroll
    for (int ni = 0; ni < NI; ni++) bfr[ni] = ldsfrag(Bcur + BHALF, rB + ni * 16, g);
#pragma unroll
    for (int mi = 0; mi < 4; mi++) afr[mi] = ldsfrag(Acur + AHALF, rA + mi * 16, g);
    if (kt + 2 < NT) stage_half<2>(Acur, Ag, K, (kt + 2) * 64, tid);
    __builtin_amdgcn_s_barrier();
    asm volatile("s_waitcnt lgkmcnt(0)" ::: "memory");
    __builtin_amdgcn_s_setprio(1);
#pragma unroll
    for (int mi = 0; mi < 4; mi++)
#pragma unroll
      for (int ni = 0; ni < NI; ni++)
        acc[mi][ni] = __builtin_amdgcn_mfma_f32_16x16x32_bf16(afr[mi], bfr[ni], acc[mi][ni], 0, 0, 0);
    __builtin_amdgcn_s_setprio(0);
    __builtin_amdgcn_s_barrier();
    // ---- phase 3: (kk1, mh1); stage Bh0(kt+2); counted wait
#pragma unroll
    for (int mi = 0; mi < 4; mi++) afr[mi] = ldsfrag(Acur + AHALF, rA + 64 + mi * 16, g);
    if (kt + 2 < NT) stage_half<NLB>(Bcur, Bg, K, (kt + 2) * 64, tid);
    __builtin_amdgcn_s_barrier();
    asm volatile("s_waitcnt lgkmcnt(0)" ::: "memory");
    __builtin_amdgcn_s_setprio(1);
#pragma unroll
    for (int mi = 0; mi < 4; mi++)
#pragma unroll
      for (int ni = 0; ni < NI; ni++)
        acc[4 + mi][ni] = __builtin_amdgcn_mfma_f32_16x16x32_bf16(afr[mi], bfr[ni], acc[4 + mi][ni], 0, 0, 0);
    __builtin_amdgcn_s_setprio(0);
    if (kt < NT - 1) {
      if (kt + 2 < NT) waitvm<2 * PAIR>();
      else             waitvm<PAIR>();
    }
    __builtin_amdgcn_s_barrier();
  }
#pragma unroll
  for (int mi = 0; mi < 8; mi++)
#pragma unroll
    for (int ni = 0; ni < NI; ni++) {
      int row0 = m0 + wm * 128 + mi * 16 + ((lane >> 4) << 2);
      int col = n0 + wn * (BN / 4) + ni * 16 + (lane & 15);
#pragma unroll
      for (int j = 0; j < 4; j++) {
        if constexpr (sizeof(CT) == 2)
          C[(size_t)(row0 + j) * N + col] = f2bf(acc[mi][ni][j]);
        else
          C[(size_t)(row0 + j) * N + col] = acc[mi][ni][j];
      }
    }
}

// ---------------------------------------------------------------- 128x128 bf16 GEMM (m97 structure)
template <typename CT>
__global__ __launch_bounds__(256) void gemm_bt(const u16t* __restrict__ A,
                                               const u16t* __restrict__ Bt,
                                               CT* __restrict__ C,
                                               int M, int N, int K) {
  __shared__ __align__(16) char As[128 * 64];
  __shared__ __align__(16) char Bs[128 * 64];
  int tid = threadIdx.x;
  int lane = tid & 63;
  int w = tid >> 6;
  int cpx = gridDim.x >> 3;
  int wgid = ((int)blockIdx.x & 7) * cpx + ((int)blockIdx.x >> 3);
  int mtiles = M >> 7;
  int bm = wgid % mtiles;
  int bn = wgid / mtiles;
  int m0 = bm << 7, n0 = bn << 7;
  int wr = (w >> 1) * 64, wc = (w & 1) * 64;

  const f32x4 fz = {0.f, 0.f, 0.f, 0.f};
  f32x4 acc[4][4];
#pragma unroll
  for (int i = 0; i < 4; i++)
#pragma unroll
    for (int j = 0; j < 4; j++) acc[i][j] = fz;

  for (int k0 = 0; k0 < K; k0 += 32) {
    __syncthreads();
#pragma unroll
    for (int i = 0; i < 2; i++) {
      int idx = i * 256 + tid;
      int r = idx >> 2, c = idx & 3;
      int csrc = c ^ ((r >> 1) & 3);
      gload_lds16(A + (size_t)(m0 + r) * K + k0 + csrc * 8, As + idx * 16);
      gload_lds16(Bt + (size_t)(n0 + r) * K + k0 + csrc * 8, Bs + idx * 16);
    }
    __syncthreads();
    s16x8 af[4], bf[4];
    int g = lane >> 4;
#pragma unroll
    for (int mi = 0; mi < 4; mi++) {
      int r = wr + mi * 16 + (lane & 15);
      af[mi] = *(const s16x8*)(As + r * 64 + ((g ^ ((r >> 1) & 3)) << 4));
    }
#pragma unroll
    for (int ni = 0; ni < 4; ni++) {
      int r = wc + ni * 16 + (lane & 15);
      bf[ni] = *(const s16x8*)(Bs + r * 64 + ((g ^ ((r >> 1) & 3)) << 4));
    }
#pragma unroll
    for (int mi = 0; mi < 4; mi++)
#pragma unroll
      for (int ni = 0; ni < 4; ni++)
        acc[mi][ni] = __builtin_amdgcn_mfma_f32_16x16x32_bf16(af[mi], bf[ni], acc[mi][ni], 0, 0, 0);
  }
#pragma unroll
  for (int mi = 0; mi < 4; mi++)
#pragma unroll
    for (int ni = 0; ni < 4; ni++) {
      int row0 = m0 + wr + mi * 16 + ((lane >> 4) << 2);
      int col = n0 + wc + ni * 16 + (lane & 15);
#pragma unroll
      for (int j = 0; j < 4; j++) {
        if constexpr (sizeof(CT) == 2)
          C[(size_t)(row0 + j) * N + col] = f2bf(acc[mi][ni][j]);
        else
          C[(size_t)(row0 + j) * N + col] = acc[mi][ni][j];
      }
    }
}

// ------------------------------------------------- fused RMSNorm + RoPE for Q and K
__global__ __launch_bounds__(256) void qk_norm_rope(const u16t* __restrict__ Cqkv,
                                                    const float* __restrict__ rope,
                                                    const float* __restrict__ qw,
                                                    const float* __restrict__ kw,
                                                    u16t* __restrict__ Qb,   // (B,H,S,D)
                                                    u16t* __restrict__ Kb,   // (B,KV,S,D)
                                                    u16t* __restrict__ Gs,   // (B,S,H*D)
                                                    float* __restrict__ present) {
  int wid = blockIdx.x * 4 + (threadIdx.x >> 6);
  int lane = threadIdx.x & 63;
  const int NQ = BB * SS * HH; // 65536
  if (wid < NQ) {
    int b = wid >> 15;          // S*H = 32768
    int rem = wid & 32767;
    int s = rem >> 4, h = rem & 15;
    const u16t* base = Cqkv + (size_t)(b * SS + s) * NQKV + h * 256;
    float xlo = bf2f(base[lane]), xhi = bf2f(base[64 + lane]);
    float ss = xlo * xlo + xhi * xhi;
    ss += __shfl_xor(ss, 1);  ss += __shfl_xor(ss, 2);  ss += __shfl_xor(ss, 4);
    ss += __shfl_xor(ss, 8);  ss += __shfl_xor(ss, 16); ss += __shfl_xor(ss, 32);
    float r = rsqrtf(ss * (1.f / 128.f) + 1e-6f);
    float qlo = xlo * r * (1.f + qw[lane]);
    float qhi = xhi * r * (1.f + qw[64 + lane]);
    const float* cs = rope + (size_t)s * 256;
    float clo = cs[lane], chi = cs[64 + lane];
    float slo = cs[128 + lane], shi = cs[192 + lane];
    // 1/sqrt(128) * log2(e): scores land in log2 units -> exp2 in attention
    const float SC = 0.08838834764831845f * 1.4426950408889634f;
    float olo = (qlo * clo - qhi * slo) * SC;
    float ohi = (qhi * chi + qlo * shi) * SC;
    size_t qoff = (((size_t)b * HH + h) * SS + s) * DD;
    Qb[qoff + lane] = f2bf(olo);
    Qb[qoff + 64 + lane] = f2bf(ohi);
    float glo = bf2f(base[128 + lane]), ghi = bf2f(base[192 + lane]);
    size_t goff = ((size_t)(b * SS + s)) * (HH * DD) + h * DD;
    Gs[goff + lane] = f2bf(1.f / (1.f + __expf(-glo)));
    Gs[goff + 64 + lane] = f2bf(1.f / (1.f + __expf(-ghi)));
  } else {
    int wid2 = wid - NQ;        // (b, s, kv): per b = S*KV = 8192
    int b = wid2 >> 13;
    int rem = wid2 & 8191;
    int s = rem >> 2, kv = rem & 3;
    const u16t* base = Cqkv + (size_t)(b * SS + s) * NQKV + 4096 + kv * 128;
    float xlo = bf2f(base[lane]), xhi = bf2f(base[64 + lane]);
    float ss = xlo * xlo + xhi * xhi;
    ss += __shfl_xor(ss, 1);  ss += __shfl_xor(ss, 2);  ss += __shfl_xor(ss, 4);
    ss += __shfl_xor(ss, 8);  ss += __shfl_xor(ss, 16); ss += __shfl_xor(ss, 32);
    float r = rsqrtf(ss * (1.f / 128.f) + 1e-6f);
    float klo = xlo * r * (1.f + kw[lane]);
    float khi = xhi * r * (1.f + kw[64 + lane]);
    const float* cs = rope + (size_t)s * 256;
    float clo = cs[lane], chi = cs[64 + lane];
    float slo = cs[128 + lane], shi = cs[192 + lane];
    float olo = klo * clo - khi * slo;
    float ohi = khi * chi + klo * shi;
    size_t koff = (((size_t)b * KVH + kv) * SS + s) * DD;
    Kb[koff + lane] = f2bf(olo);
    Kb[koff + 64 + lane] = f2bf(ohi);
    size_t poff = (((size_t)(b * 2 * KVH + kv)) * SS + s) * DD;
    present[poff + lane] = olo;
    present[poff + 64 + lane] = ohi;
  }
}

// ------------------------------------------------- V: present write + V^T bf16 (B,KV,D,S)
__global__ __launch_bounds__(256) void v_write(const u16t* __restrict__ Cqkv,
                                               float* __restrict__ present,
                                               u16t* __restrict__ Vtb) {
  __shared__ float lds[128 * 65];
  int t = threadIdx.x;
  int b = blockIdx.x >> 7;
  int kv = (blockIdx.x >> 5) & 3;
  int s0 = (blockIdx.x & 31) << 6;
#pragma unroll
  for (int i = 0; i < 32; i++) {
    int idx = i * 256 + t;
    int sp = idx >> 7, d = idx & 127;
    float v = bf2f(Cqkv[(size_t)(b * SS + s0 + sp) * NQKV + 4608 + kv * 128 + d]);
    present[(((size_t)(b * 2 * KVH + KVH + kv)) * SS + s0 + sp) * DD + d] = v;
    lds[d * 65 + sp] = v;
  }
  __syncthreads();
#pragma unroll
  for (int i = 0; i < 8; i++) {
    int d = i * 16 + (t >> 4);
    int sp = (t & 15) * 4;
    s16x4 pk;
    pk[0] = (short)f2bf(lds[d * 65 + sp + 0]);
    pk[1] = (short)f2bf(lds[d * 65 + sp + 1]);
    pk[2] = (short)f2bf(lds[d * 65 + sp + 2]);
    pk[3] = (short)f2bf(lds[d * 65 + sp + 3]);
    *(s16x4*)(Vtb + ((size_t)(b * KVH + kv) * DD + d) * SS + s0 + sp) = pk;
  }
}

// ---------------------------------------------------------------- flash attention v5.1
// Paired q-tiles + K/V dbuf + swapped-QK^T in-register softmax, with all LDS
// offsets hoisted to registers (ka/va/pr/pw); per-tile addressing is a uniform
// +cur*16K fold. launch_bounds(256,2) -> VGPR cap 128.
// (defer-max REVERTED pending isolation of the round-11 failure.)
__global__ __launch_bounds__(256, 2) void attn_kernel(const u16t* __restrict__ Qb,   // (B,H,S,D) pre-scaled
                                                      const u16t* __restrict__ Kb,   // (B,KV,S,D)
                                                      const u16t* __restrict__ Vtb,  // (B,KV,D,S)
                                                      const u16t* __restrict__ Gs,   // (B,S,H*D)
                                                      u16t* __restrict__ AttG) {     // (B,S,H*D)
  __shared__ __align__(16) char Ks[2 * 16384];  // 64 rows x 256B, chunk xor (r&7)
  __shared__ __align__(16) char Vs[2 * 16384];  // V^T: 128 rows x 128B, chunk xor (d&7)
  __shared__ __align__(16) char Ps[4 * 2048];   // per-wave P: [q:16][k-granule xor (q&7)]

  int tid = threadIdx.x, lane = tid & 63, w = tid >> 6;
  int x = blockIdx.x & 7;          // XCD grouping: each XCD owns one (b,kv)
  int b = x >> 2, kv = x & 3;
  int rr = blockIdx.x >> 3;        // 0..63
  int h = kv * 4 + (rr & 3);
  int p = rr >> 2;                 // 0..15: pair {31-p, p}

  const u16t* Kbase = Kb + (((size_t)(b * KVH + kv)) * SS) * DD;
  const u16t* Vbase = Vtb + (((size_t)(b * KVH + kv)) * DD) * SS;

  auto stageK = [&](int kt, int buf) {
#pragma unroll
    for (int i = 0; i < 4; i++) {
      int idx = i * 256 + tid;
      int r_ = idx >> 4, c_ = idx & 15;
      gload_lds16(Kbase + (size_t)(kt * 64 + r_) * DD + (c_ ^ (r_ & 7)) * 8,
                  Ks + buf * 16384 + idx * 16);
    }
  };
  auto stageV = [&](int kt, int buf) {
#pragma unroll
    for (int i = 0; i < 4; i++) {
      int idx = i * 256 + tid;
      int r_ = idx >> 3, c_ = idx & 7;
      gload_lds16(Vbase + (size_t)r_ * SS + kt * 64 + (c_ ^ (r_ & 7)) * 8,
                  Vs + buf * 16384 + idx * 16);
    }
  };

  const f32x4 fz = {0.f, 0.f, 0.f, 0.f};
  int g = lane >> 4;
  int q15 = lane & 15;
  int q7 = q15 & 7;
  char* pq = Ps + w * 2048 + q15 * 128;   // this lane's q-row in P
  int cur = 0;

  // ---- hoisted LDS offsets (loop-invariant; live in VGPRs)
  int ka[4][4];     // K-read: row ni*16+q15, chunk (ks*4+g)^q7
#pragma unroll
  for (int ni = 0; ni < 4; ni++)
#pragma unroll
    for (int ks = 0; ks < 4; ks++)
      ka[ni][ks] = (ni * 16 + q15) * 256 + (((ks * 4 + g) ^ q7) << 4);
  int va[2][8];     // V-read: row f*16+q15 (d&7 == q7), chunk (ks2*4+g)^q7
#pragma unroll
  for (int ks2 = 0; ks2 < 2; ks2++)
#pragma unroll
    for (int f = 0; f < 8; f++)
      va[ks2][f] = (f * 16 + q15) * 128 + (((ks2 * 4 + g) ^ q7) << 4);
  int pr_[2];       // P-read offsets within pq
#pragma unroll
  for (int ks2 = 0; ks2 < 2; ks2++) pr_[ks2] = ((ks2 * 4 + g) ^ q7) << 4;
  int pw_[4];       // P-write offsets within pq
#pragma unroll
  for (int ni = 0; ni < 4; ni++)
    pw_[ni] = (((ni * 2 + (g >> 1)) ^ q7) << 4) + ((g & 1) << 3);

  // prologue: stage tile 0 of segment 0 into buffer 0
  stageK(0, 0);
  stageV(0, 0);

  for (int seg = 0; seg < 2; seg++) {
    int qt = (seg == 0) ? (31 - p) : p;
    const u16t* Qbase = Qb + (((size_t)(b * HH + h)) * SS + qt * 64) * DD;
    s16x8 qf[4];
    {
      const u16t* qrow = Qbase + (size_t)(w * 16 + q15) * DD + g * 8;
#pragma unroll
      for (int ks = 0; ks < 4; ks++) qf[ks] = *(const s16x8*)(qrow + ks * 32);
    }
    f32x4 acco[8];
#pragma unroll
    for (int f = 0; f < 8; f++) acco[f] = fz;
    float mrun = -INFINITY, lrun = 0.f;

    if (seg == 0) {
      asm volatile("s_waitcnt vmcnt(0)" ::: "memory");
      __builtin_amdgcn_s_barrier();
    }

    for (int kt = 0; kt <= qt; kt++) {
      bool havenext = (kt < qt) || (seg == 0);
      if (havenext) {
        int nk = (kt < qt) ? (kt + 1) : 0;   // next tile, or seg1's tile 0
        stageK(nk, cur ^ 1);
        stageV(nk, cur ^ 1);
      }
      const char* kc = Ks + (cur << 14);
      const char* vc = Vs + (cur << 14);
      // ---- swapped QK^T: accs[ni][j] = S[q = lane&15][k = ni*16+g*4+j]
      f32x4 accs[4];
#pragma unroll
      for (int ni = 0; ni < 4; ni++) accs[ni] = fz;
#pragma unroll
      for (int ni = 0; ni < 4; ni++)
#pragma unroll
        for (int ks = 0; ks < 4; ks++) {
          s16x8 bfk = *(const s16x8*)(kc + ka[ni][ks]);
          accs[ni] = __builtin_amdgcn_mfma_f32_16x16x32_bf16(bfk, qf[ks], accs[ni], 0, 0, 0);
        }
      if (kt == qt) {
        int ql = w * 16 + q15;
#pragma unroll
        for (int ni = 0; ni < 4; ni++)
#pragma unroll
          for (int j = 0; j < 4; j++) {
            int kl = ni * 16 + (g << 2) + j;
            if (kl > ql) accs[ni][j] = -1e30f;
          }
      }
      // ---- per-lane softmax (q = lane&15; 4 lanes/q combine via 2 shuffles)
      f32x4 m4 = fmax4(fmax4(accs[0], accs[1]), fmax4(accs[2], accs[3]));
      float mt = fmaxf(fmaxf(m4[0], m4[1]), fmaxf(m4[2], m4[3]));
      mt = fmaxf(mt, __shfl_xor(mt, 16));
      mt = fmaxf(mt, __shfl_xor(mt, 32));
      float mnew = fmaxf(mrun, mt);
      float alpha = __builtin_amdgcn_exp2f(mrun - mnew);
      mrun = mnew;
#pragma unroll
      for (int ni = 0; ni < 4; ni++)
#pragma unroll
        for (int j = 0; j < 4; j++)
          accs[ni][j] = __builtin_amdgcn_exp2f(accs[ni][j] - mnew);
      f32x4 s4 = (accs[0] + accs[1]) + (accs[2] + accs[3]);
      float rs = (s4[0] + s4[1]) + (s4[2] + s4[3]);
      rs += __shfl_xor(rs, 16);
      rs += __shfl_xor(rs, 32);
      lrun = lrun * alpha + rs;
      // broadcast alpha to acco's q layout (rows q = g*4+j)
      float ar[4];
#pragma unroll
      for (int j = 0; j < 4; j++) ar[j] = __shfl(alpha, (g << 2) + j);
#pragma unroll
      for (int f = 0; f < 8; f++)
#pragma unroll
        for (int j = 0; j < 4; j++) acco[f][j] *= ar[j];

      // ---- P pack (bf16 pairs along k) -> b64 LDS stores
#pragma unroll
      for (int ni = 0; ni < 4; ni++) {
        uint2 pk;
        pk.x = cvtpk_bf16(accs[ni][0], accs[ni][1]);
        pk.y = cvtpk_bf16(accs[ni][2], accs[ni][3]);
        *(uint2*)(pq + pw_[ni]) = pk;
      }
      // ---- PV
#pragma unroll
      for (int ks2 = 0; ks2 < 2; ks2++) {
        s16x8 pa = *(const s16x8*)(pq + pr_[ks2]);
#pragma unroll
        for (int f = 0; f < 8; f++) {
          s16x8 vf = *(const s16x8*)(vc + va[ks2][f]);
          acco[f] = __builtin_amdgcn_mfma_f32_16x16x32_bf16(pa, vf, acco[f], 0, 0, 0);
        }
      }
      // ---- tile boundary: next tile staged, current reads done
      if (havenext) {
        asm volatile("s_waitcnt vmcnt(0)" ::: "memory");
        __builtin_amdgcn_s_barrier();
        cur ^= 1;
      }
    }
    // ---- segment epilogue: gate + store (lrun broadcast to acco layout)
    float lr[4];
#pragma unroll
    for (int j = 0; j < 4; j++) lr[j] = __shfl(lrun, (g << 2) + j);
#pragma unroll
    for (int f = 0; f < 8; f++) {
      int d = f * 16 + q15;
#pragma unroll
      for (int j = 0; j < 4; j++) {
        int srow = qt * 64 + w * 16 + (g << 2) + j;
        float o = acco[f][j] / lr[j];
        size_t off = ((size_t)b * SS + srow) * (HH * DD) + h * DD + d;
        float gt = bf2f(Gs[off]);
        AttG[off] = f2bf(o * gt);
      }
    }
  }
}

// ---------------------------------------------------------------- launcher
extern "C" void kernel_launch(void* const* d_in, const int* in_sizes, int n_in,
                              void* d_out, int out_size, void* d_ws, size_t ws_size,
                              hipStream_t stream) {
  const float* hidden = (const float*)d_in[0];
  const float* rope   = (const float*)d_in[2];
  const float* Wq     = (const float*)d_in[5];
  const float* Wk     = (const float*)d_in[6];
  const float* Wv     = (const float*)d_in[7];
  const float* Wo     = (const float*)d_in[8];
  const float* qw     = (const float*)d_in[9];
  const float* kw     = (const float*)d_in[10];
  float* out = (float*)d_out;
  float* present = out + (size_t)BB * SS * HIDD; // 8,388,608

  char* ws = (char*)d_ws;
  u16t* Xb    = (u16t*)(ws);                              // 4096x2048 bf16   16.78MB
  u16t* Wt    = (u16t*)(ws + 16777216);                   // 5120x2048 bf16   20.97MB
  u16t* Wot   = (u16t*)(ws + 37748736);                   // 2048x2048 bf16    8.39MB
  u16t* Cqkv  = (u16t*)(ws + 46137344);                   // 4096x5120 bf16   41.94MB
  u16t* Qb    = (u16t*)(ws + 88080384);                   // (B,H,S,D) bf16   16.78MB
  u16t* Kb    = (u16t*)(ws + 104857600);                  // (B,KV,S,D) bf16   4.19MB
  u16t* Vtb   = (u16t*)(ws + 109051904);                  // (B,KV,D,S) bf16   4.19MB
  u16t* Gs    = (u16t*)(ws + 113246208);                  // (B,S,H*D) bf16   16.78MB
  u16t* AttG  = Xb;  // alias: Xb dead after QKV GEMM; AttG written by attention

  (void)hipFuncSetAttribute(reinterpret_cast<const void*>(gemm8<256, u16t>),
                            hipFuncAttributeMaxDynamicSharedMemorySize, 131072);
  (void)hipFuncSetAttribute(reinterpret_cast<const void*>(gemm8<128, float>),
                            hipFuncAttributeMaxDynamicSharedMemorySize, 98304);

  // 1+2. fused prep: cast hidden + all weight transposes (one launch)
  prep_all<<<8192 + 3584, 256, 0, stream>>>(hidden, Wq, Wk, Wv, Wo, Xb, Wt, Wot);
  // 3a. Q projection (N=4096): 256^2 8-phase, grid 16x16 = 256 = exactly 1 block/CU
  gemm8<256, u16t><<<(MM / 256) * (4096 / 256), 512, 131072, stream>>>(Xb, Wt, Cqkv, MM, NQKV, HIDD);
  // 3b. K+V projection (N=1024): 128^2 m97, grid 32x8 = 256 = exactly 1 block/CU
  gemm_bt<u16t><<<(MM / 128) * (1024 / 128), 256, 0, stream>>>(
      Xb, Wt + (size_t)4096 * HIDD, Cqkv + 4096, MM, NQKV, HIDD);
  // 4. Q/K norm+rope (+present K, +sigmoid gate); V writer (+present V, +V^T)
  qk_norm_rope<<<(BB * SS * (HH + KVH)) / 4, 256, 0, stream>>>(Cqkv, rope, qw, kw, Qb, Kb, Gs, present);
  v_write<<<BB * KVH * (SS / 64), 256, 0, stream>>>(Cqkv, present, Vtb);
  // 5. flash attention v5.1: hoisted LDS addressing (defer-max reverted)
  attn_kernel<<<BB * HH * (SS / 128), 256, 0, stream>>>(Qb, Kb, Vtb, Gs, AttG);
  // 6. output projection -> d_out: 256x128 8-phase, grid 16x16 = 256 = 1 block/CU
  gemm8<128, float><<<(MM / 256) * (HIDD / 128), 512, 98304, stream>>>(AttG, Wot, out, MM, HIDD, HIDD);
}